// Round 14
// baseline (590.481 us; speedup 1.0000x reference)
//
#include <hip/hip_runtime.h>
#include <hip/hip_bf16.h>
#include <math.h>

#define BN_EPS 1e-5f
#define NCHUNK 256

typedef __attribute__((ext_vector_type(8)))  short short8v;
typedef __attribute__((ext_vector_type(16))) float f32x16;

__device__ __forceinline__ unsigned short f2bf(float f){
  union { float f; unsigned u; } v; v.f = f;
  unsigned r = v.u + 0x7FFFu + ((v.u >> 16) & 1u);
  return (unsigned short)(r >> 16);
}
__device__ __forceinline__ float2 bfpair(unsigned u){
  union { unsigned u; float f; } lo, hi;
  lo.u = u << 16;
  hi.u = u & 0xFFFF0000u;
  return make_float2(lo.f, hi.f);
}
__device__ __forceinline__ unsigned packbf(float a, float b){
  return (unsigned)f2bf(a) | ((unsigned)f2bf(b) << 16);
}
// monotonic float->uint map for atomicMax (order-preserving for all finite floats)
__device__ __forceinline__ unsigned fmap(float f){
  union { float f; unsigned u; } v; v.f = f;
  return (v.u & 0x80000000u) ? ~v.u : (v.u | 0x80000000u);
}
__device__ __forceinline__ float funmap(unsigned u){
  union { unsigned u; float f; } v;
  v.u = (u & 0x80000000u) ? (u & 0x7FFFFFFFu) : ~u;
  return v.f;
}

// ========== K1: chunk_hist (blocks 0..NCHUNK-1)  ||  bn_part (blocks NCHUNK..NCHUNK+511) ==========
__global__ __launch_bounds__(256) void k_hist_bn(const int* __restrict__ dst,
                                                 int* __restrict__ hist2, int E, int NB, int CH,
                                                 const float* __restrict__ x,
                                                 float* __restrict__ part, int total4){
  int tid = threadIdx.x;
  if (blockIdx.x < NCHUNK){
    __shared__ int lh[512];
    for (int i = tid; i < NB; i += 256) lh[i] = 0;
    __syncthreads();
    int c = blockIdx.x;
    int e0 = c*CH, e1 = min(e0 + CH, E);
    for (int e = e0 + tid; e < e1; e += 256)
      atomicAdd(&lh[dst[e] >> 8], 1);
    __syncthreads();
    for (int i = tid; i < NB; i += 256)
      hist2[c*NB + i] = lh[i];
  } else {
    const float4* x4 = (const float4*)x;
    int bb = blockIdx.x - NCHUNK;          // 0..511
    int stride = 512 * 256;
    float4 s = make_float4(0.f,0.f,0.f,0.f);
    float4 q = make_float4(0.f,0.f,0.f,0.f);
    for (int idx = bb*256 + tid; idx < total4; idx += stride){
      float4 v = x4[idx];
      s.x += v.x; s.y += v.y; s.z += v.z; s.w += v.w;
      q.x += v.x*v.x; q.y += v.y*v.y; q.z += v.z*v.z; q.w += v.w*v.w;
    }
    __shared__ float4 shs[256], shq[256];
    shs[tid] = s; shq[tid] = q;
    __syncthreads();
    if (tid < 32){
      int c4 = tid;
      float4 ts = shs[c4], tq = shq[c4];
      #pragma unroll
      for (int j = 1; j < 8; ++j){
        float4 os = shs[c4 + j*32], oq = shq[c4 + j*32];
        ts.x += os.x; ts.y += os.y; ts.z += os.z; ts.w += os.w;
        tq.x += oq.x; tq.y += oq.y; tq.z += oq.z; tq.w += oq.w;
      }
      float* pb = part + (size_t)bb * 256;
      *(float4*)(pb + c4*4)       = ts;
      *(float4*)(pb + 128 + c4*4) = tq;
    }
  }
}

// ========== K2: chunk_scan (blk 0) || bn_reduce (blk 1) || gbounds (blk 2,3) ==========
__global__ __launch_bounds__(512) void k_scan_red_gb(const int* __restrict__ hist2,
                                                     int* __restrict__ offs2,
                                                     int* __restrict__ bbase, int NB, int E,
                                                     const float* __restrict__ part,
                                                     const float* __restrict__ gamma,
                                                     const float* __restrict__ beta,
                                                     float* __restrict__ scale,
                                                     float* __restrict__ shift, int N,
                                                     const int* __restrict__ batch,
                                                     int* __restrict__ gstart, int G){
  int t = threadIdx.x;
  if (blockIdx.x == 0){
    __shared__ int tot[512];
    int b = t;
    int total = 0;
    if (b < NB){
      for (int c = 0; c < NCHUNK; c += 8){
        int h0 = hist2[(c+0)*NB + b], h1 = hist2[(c+1)*NB + b];
        int h2 = hist2[(c+2)*NB + b], h3 = hist2[(c+3)*NB + b];
        int h4 = hist2[(c+4)*NB + b], h5 = hist2[(c+5)*NB + b];
        int h6 = hist2[(c+6)*NB + b], h7 = hist2[(c+7)*NB + b];
        total += ((h0+h1)+(h2+h3)) + ((h4+h5)+(h6+h7));
      }
    }
    tot[b] = (b < NB) ? total : 0;
    __syncthreads();
    int v = tot[b];
    for (int d = 1; d < 512; d <<= 1){
      int u = (b >= d) ? tot[b-d] : 0;
      __syncthreads();
      tot[b] += u;
      __syncthreads();
    }
    if (b < NB){
      int base = tot[b] - v;
      bbase[b] = base;
      int run = base;
      for (int c = 0; c < NCHUNK; ++c){
        offs2[c*NB + b] = run;
        run += hist2[c*NB + b];
      }
    }
    if (b == 0) bbase[NB] = E;
  } else if (blockIdx.x == 1){
    if (t < 256){
      float a0=0.f,a1=0.f,a2=0.f,a3=0.f,a4=0.f,a5=0.f,a6=0.f,a7=0.f;
      for (int b = 0; b < 512; b += 8){
        a0 += part[(size_t)(b+0)*256 + t];
        a1 += part[(size_t)(b+1)*256 + t];
        a2 += part[(size_t)(b+2)*256 + t];
        a3 += part[(size_t)(b+3)*256 + t];
        a4 += part[(size_t)(b+4)*256 + t];
        a5 += part[(size_t)(b+5)*256 + t];
        a6 += part[(size_t)(b+6)*256 + t];
        a7 += part[(size_t)(b+7)*256 + t];
      }
      float acc = ((a0+a1)+(a2+a3)) + ((a4+a5)+(a6+a7));
      __shared__ float sh[256];
      sh[t] = acc;
      __syncthreads();
      if (t < 128){
        float mu  = sh[t] / (float)N;
        float var = sh[t+128] / (float)N - mu*mu;
        float sc  = gamma[t] * rsqrtf(var + BN_EPS);
        scale[t] = sc;
        shift[t] = beta[t] - mu*sc;
      }
    }
  } else {
    int g = (blockIdx.x - 2)*512 + t;
    if (g <= G){
      int lo = 0, hi = N;
      while (lo < hi){ int mid = (lo+hi)>>1; if (batch[mid] < g) lo = mid+1; else hi = mid; }
      gstart[g] = lo;
    }
  }
}

// ---- P3: scatter via LDS cursors (no global atomics) ----
__global__ __launch_bounds__(256) void chunk_scatter(const int* __restrict__ src,
                                                     const int* __restrict__ dst,
                                                     const int* __restrict__ offs2,
                                                     unsigned* __restrict__ ebuf,
                                                     int E, int NB, int CH){
  __shared__ int lcur[512];
  int c = blockIdx.x;
  for (int i = threadIdx.x; i < NB; i += 256) lcur[i] = offs2[c*NB + i];
  __syncthreads();
  int e0 = c*CH, e1 = min(e0 + CH, E);
  for (int e = e0 + threadIdx.x; e < e1; e += 256){
    int d = dst[e];
    int b = d >> 8;
    int pos = atomicAdd(&lcur[b], 1);
    ebuf[pos] = ((unsigned)(d & 255) << 24) | (unsigned)src[e];
  }
}

// ========== K3: bucket_sort (blks 0..NB-1) || prep_w (NB..NB+191) || prep_bias0 (NB+192) ==========
__global__ __launch_bounds__(256) void k_sort_prep(const unsigned* __restrict__ ebuf,
                                                   const int* __restrict__ bbase,
                                                   int* __restrict__ csrs,
                                                   int* __restrict__ rowstart,
                                                   float* __restrict__ dinv,
                                                   int N, int E, int NB,
                                                   const float* __restrict__ W0,
                                                   const float* __restrict__ W1,
                                                   const float* __restrict__ W2,
                                                   const float* __restrict__ scale,
                                                   unsigned short* __restrict__ Wh,
                                                   const float* __restrict__ b0,
                                                   const float* __restrict__ shift,
                                                   float* __restrict__ bias0p){
  int tid = threadIdx.x;
  if ((int)blockIdx.x < NB){
    int b = blockIdx.x;
    int base = bbase[b];
    int end  = bbase[b+1];
    int len  = end - base;
    __shared__ int cnt[256];
    __shared__ int pref[256];
    cnt[tid] = 0;
    __syncthreads();
    for (int i = tid; i < len; i += 256)
      atomicAdd(&cnt[ebuf[base + i] >> 24], 1);
    __syncthreads();
    int v = cnt[tid];
    pref[tid] = v;
    __syncthreads();
    for (int d = 1; d < 256; d <<= 1){
      int u = (tid >= d) ? pref[tid-d] : 0;
      __syncthreads();
      pref[tid] += u;
      __syncthreads();
    }
    int excl = pref[tid] - v;
    int node = b*256 + tid;
    if (node < N){
      rowstart[node] = base + excl;
      dinv[node] = rsqrtf((float)v + 1.0f);
    }
    cnt[tid] = excl;
    __syncthreads();
    for (int i = tid; i < len; i += 256){
      unsigned r = ebuf[base + i];
      int pos = atomicAdd(&cnt[r >> 24], 1);
      csrs[base + pos] = (int)(r & 0xFFFFFFu);
    }
    if (b == NB-1 && tid == 0) rowstart[N] = E;
  } else if ((int)blockIdx.x < NB + 192){
    int idx = (blockIdx.x - NB)*256 + tid;   // 0..49151 = 3*16384
    int l = idx >> 14, r = idx & 16383, c = r >> 7, k = r & 127;
    const float* W = (l==0) ? W0 : (l==1) ? W1 : W2;
    float v = W[k*128 + c];
    if (l == 0) v *= scale[k];
    Wh[idx] = f2bf(v);
  } else {
    __shared__ float sh[128];
    if (tid < 128) sh[tid] = shift[tid];
    __syncthreads();
    if (tid < 128){
      float s = b0[tid];
      for (int c = 0; c < 128; ++c) s += sh[c] * W0[c*128 + tid];
      bias0p[tid] = s;
    }
  }
}

// ---------------- lean MFMA GEMM: C[N,128] (bf16) = A @ W_hi ----------------
template<int CVT>
__global__ __launch_bounds__(512) void gemm_mfma(
    const float* __restrict__ A32, const unsigned short* __restrict__ A16,
    const unsigned short* __restrict__ Bh, unsigned short* __restrict__ C, int N){
  __shared__ unsigned short Ah[64*128];
  int tid = threadIdx.x;
  int r0 = blockIdx.x * 64;
  int w = tid >> 6, lane = tid & 63;
  int rt = w & 1;
  int ct = (w >> 1) * 32;
  int lrow = 32*rt + (lane & 31);
  int khalf = lane >> 5;
  int c0 = ct + (lane & 31);
  const unsigned short* bh0 = Bh + (size_t)c0*128 + khalf*8;

  short8v bhf[8];
  #pragma unroll
  for (int s = 0; s < 8; ++s) bhf[s] = *(const short8v*)(bh0 + s*16);

  if (CVT){
    #pragma unroll
    for (int it = 0; it < 4; ++it){
      int idx = tid + it*512;
      int row = idx >> 5;
      int c4  = idx & 31;
      int r = r0 + row;
      float4 av = (r < N) ? *(const float4*)(A32 + (size_t)r*128 + c4*4)
                          : make_float4(0.f,0.f,0.f,0.f);
      int byte0 = (c4*8) ^ ((row & 15) << 4);
      uint2 p = make_uint2(packbf(av.x, av.y), packbf(av.z, av.w));
      *(uint2*)((char*)Ah + row*256 + byte0) = p;
    }
  } else {
    #pragma unroll
    for (int it = 0; it < 2; ++it){
      int idx = tid + it*512;
      int row = idx >> 4;
      int c8  = idx & 15;
      int r = r0 + row;
      uint4 v = (r < N) ? *(const uint4*)(A16 + (size_t)r*128 + c8*8)
                        : make_uint4(0,0,0,0);
      int byte0 = (c8*16) ^ ((row & 15) << 4);
      *(uint4*)((char*)Ah + row*256 + byte0) = v;
    }
  }
  __syncthreads();

  f32x16 acc = {};
  const char* AhB = (const char*)Ah + lrow*256;
  int sw = (lrow & 15) << 4;
  #pragma unroll
  for (int s = 0; s < 8; ++s){
    int abyte = (s*32 + khalf*16) ^ sw;
    short8v a = *(const short8v*)(AhB + abyte);
    acc = __builtin_amdgcn_mfma_f32_32x32x16_bf16(a, bhf[s], acc, 0, 0, 0);
  }

  #pragma unroll
  for (int r = 0; r < 16; ++r){
    int row = r0 + 32*rt + (r & 3) + 8*(r >> 2) + 4*khalf;
    if (row < N) C[(size_t)row*128 + c0] = f2bf(acc[r]);
  }
}

// ------- fused aggregation + squash + attention + per-graph readout -------
// Half-wave per node (8 nodes/block). Readout accumulated in LDS per graph-slot
// (batch sorted -> <=8 graphs per block; global-atomic fallback otherwise),
// then flushed with ~1 slot x 384 global atomics per block.
// grepF: [0..G*128) = wsum (summed over layers), [G*128..2*G*128) = raw sums.
// grepM: per-layer monotonic-uint max buffer (decoded+summed in classify).
template<int LAST>
__global__ __launch_bounds__(256) void gather_ro(
    const unsigned short* __restrict__ m, const int* __restrict__ rowstart,
    const int* __restrict__ csrs, const float* __restrict__ dinv,
    const float* __restrict__ bias, const float* __restrict__ tar,
    const int* __restrict__ batch, unsigned short* __restrict__ h,
    float* __restrict__ grepF, unsigned* __restrict__ grepM, int N, int G){
  __shared__ float lws[8][128];
  __shared__ float lsm[8][128];
  __shared__ unsigned lmx[8][128];
  __shared__ int smax;
  int tid = threadIdx.x;
  for (int i = tid; i < 8*128; i += 256){
    ((float*)lws)[i] = 0.f; ((float*)lsm)[i] = 0.f; ((unsigned*)lmx)[i] = 0u;
  }
  if (tid == 0) smax = 0;
  __syncthreads();

  int node = blockIdx.x*8 + (tid >> 5);
  int lane = tid & 31;
  int nf = blockIdx.x*8; if (nf >= N) nf = N-1;
  int g0 = batch[nf];
  bool active = (node < N);
  float h0=0.f,h1=0.f,h2=0.f,h3=0.f,at=0.f;
  int g = g0, slot = 0;

  if (active){
    const uint2* m2 = (const uint2*)m;
    float dv = dinv[node];
    float sn = dv*dv;
    uint2 sv = m2[(size_t)node*32 + lane];
    float2 p0 = bfpair(sv.x), p1 = bfpair(sv.y);
    float a0 = p0.x*sn, a1 = p0.y*sn, a2 = p1.x*sn, a3 = p1.y*sn;
    int j0 = rowstart[node], j1 = rowstart[node+1];

    for (int base = j0; base < j1; base += 32){
      int cnt = j1 - base; if (cnt > 32) cnt = 32;
      int sidx = 0; float swt = 0.f;
      if (lane < cnt){
        sidx = csrs[base + lane];
        swt  = dinv[sidx] * dv;
      }
      int t = 0;
      for (; t + 4 <= cnt; t += 4){
        int s0 = __shfl(sidx, t, 32),   s1 = __shfl(sidx, t+1, 32);
        int s2 = __shfl(sidx, t+2, 32), s3 = __shfl(sidx, t+3, 32);
        float w0 = __shfl(swt, t, 32),   w1 = __shfl(swt, t+1, 32);
        float w2 = __shfl(swt, t+2, 32), w3 = __shfl(swt, t+3, 32);
        uint2 u0 = m2[(size_t)s0*32 + lane];
        uint2 u1 = m2[(size_t)s1*32 + lane];
        uint2 u2 = m2[(size_t)s2*32 + lane];
        uint2 u3 = m2[(size_t)s3*32 + lane];
        float2 q0, q1;
        q0 = bfpair(u0.x); q1 = bfpair(u0.y);
        a0 += w0*q0.x; a1 += w0*q0.y; a2 += w0*q1.x; a3 += w0*q1.y;
        q0 = bfpair(u1.x); q1 = bfpair(u1.y);
        a0 += w1*q0.x; a1 += w1*q0.y; a2 += w1*q1.x; a3 += w1*q1.y;
        q0 = bfpair(u2.x); q1 = bfpair(u2.y);
        a0 += w2*q0.x; a1 += w2*q0.y; a2 += w2*q1.x; a3 += w2*q1.y;
        q0 = bfpair(u3.x); q1 = bfpair(u3.y);
        a0 += w3*q0.x; a1 += w3*q0.y; a2 += w3*q1.x; a3 += w3*q1.y;
      }
      if (cnt - t >= 2){
        int s0 = __shfl(sidx, t, 32), s1 = __shfl(sidx, t+1, 32);
        float w0 = __shfl(swt, t, 32), w1 = __shfl(swt, t+1, 32);
        uint2 u0 = m2[(size_t)s0*32 + lane];
        uint2 u1 = m2[(size_t)s1*32 + lane];
        float2 q0 = bfpair(u0.x), q1 = bfpair(u0.y);
        a0 += w0*q0.x; a1 += w0*q0.y; a2 += w0*q1.x; a3 += w0*q1.y;
        q0 = bfpair(u1.x); q1 = bfpair(u1.y);
        a0 += w1*q0.x; a1 += w1*q0.y; a2 += w1*q1.x; a3 += w1*q1.y;
        t += 2;
      }
      if (t < cnt){
        int s0 = __shfl(sidx, t, 32);
        float w0 = __shfl(swt, t, 32);
        uint2 u0 = m2[(size_t)s0*32 + lane];
        float2 q0 = bfpair(u0.x), q1 = bfpair(u0.y);
        a0 += w0*q0.x; a1 += w0*q0.y; a2 += w0*q1.x; a3 += w0*q1.y;
      }
    }

    float4 bv = ((const float4*)bias)[lane];
    a0 += bv.x; a1 += bv.y; a2 += bv.z; a3 += bv.w;
    float n2 = a0*a0 + a1*a1 + a2*a2 + a3*a3;
    #pragma unroll
    for (int o = 16; o > 0; o >>= 1) n2 += __shfl_xor(n2, o);
    float sc = (n2/(1.f+n2)) * rsqrtf(n2 + 1e-12f);
    h0 = a0*sc; h1 = a1*sc; h2 = a2*sc; h3 = a3*sc;
    if (!LAST)
      ((uint2*)(h + (size_t)node*128))[lane] = make_uint2(packbf(h0,h1), packbf(h2,h3));
    float4 tv = ((const float4*)tar)[lane];
    at = h0*tv.x + h1*tv.y + h2*tv.z + h3*tv.w;
    #pragma unroll
    for (int o = 16; o > 0; o >>= 1) at += __shfl_xor(at, o);
    g = batch[node];
    slot = g - g0;
  }

  if (active){
    if (slot < 8){
      int f = lane*4;
      atomicAdd(&lws[slot][f+0], at*h0); atomicAdd(&lws[slot][f+1], at*h1);
      atomicAdd(&lws[slot][f+2], at*h2); atomicAdd(&lws[slot][f+3], at*h3);
      atomicAdd(&lsm[slot][f+0], h0);    atomicAdd(&lsm[slot][f+1], h1);
      atomicAdd(&lsm[slot][f+2], h2);    atomicAdd(&lsm[slot][f+3], h3);
      atomicMax(&lmx[slot][f+0], fmap(h0)); atomicMax(&lmx[slot][f+1], fmap(h1));
      atomicMax(&lmx[slot][f+2], fmap(h2)); atomicMax(&lmx[slot][f+3], fmap(h3));
      if (lane == 0) atomicMax(&smax, slot);
    } else {
      // pathological fallback (graph span >8 within one block)
      int f = lane*4;
      atomicAdd(&grepF[(size_t)g*128 + f+0], at*h0);
      atomicAdd(&grepF[(size_t)g*128 + f+1], at*h1);
      atomicAdd(&grepF[(size_t)g*128 + f+2], at*h2);
      atomicAdd(&grepF[(size_t)g*128 + f+3], at*h3);
      atomicAdd(&grepF[((size_t)G + g)*128 + f+0], h0);
      atomicAdd(&grepF[((size_t)G + g)*128 + f+1], h1);
      atomicAdd(&grepF[((size_t)G + g)*128 + f+2], h2);
      atomicAdd(&grepF[((size_t)G + g)*128 + f+3], h3);
      atomicMax(&grepM[(size_t)g*128 + f+0], fmap(h0));
      atomicMax(&grepM[(size_t)g*128 + f+1], fmap(h1));
      atomicMax(&grepM[(size_t)g*128 + f+2], fmap(h2));
      atomicMax(&grepM[(size_t)g*128 + f+3], fmap(h3));
    }
  }
  __syncthreads();
  int ms = smax;
  if (tid < 128){
    for (int s = 0; s <= ms; ++s){
      int gg = g0 + s;
      if (gg < G){
        float vw = lws[s][tid], vs = lsm[s][tid];
        unsigned vm = lmx[s][tid];
        atomicAdd(&grepF[(size_t)gg*128 + tid], vw);
        atomicAdd(&grepF[((size_t)G + gg)*128 + tid], vs);
        if (vm) atomicMax(&grepM[(size_t)gg*128 + tid], vm);
      }
    }
  }
}

// ---------------- classifier head + log_softmax ----------------
__global__ __launch_bounds__(128) void classify(const float* __restrict__ grepF,
                                                const unsigned* __restrict__ grepM,
                                                const int* __restrict__ gstart,
                                                const float* __restrict__ w1, const float* __restrict__ b1,
                                                const float* __restrict__ w2, const float* __restrict__ b2,
                                                float* __restrict__ out, int G){
  int g = blockIdx.x, t = threadIdx.x;
  __shared__ float gr[384];
  int a = gstart[g], b = gstart[g+1];
  int cnt = b - a;
  float inv = 1.f / fmaxf((float)cnt, 1.f);
  gr[t]       = grepF[(size_t)g*128 + t];
  gr[128 + t] = grepF[((size_t)G + g)*128 + t] * inv;
  float mx = 0.f;
  if (cnt > 0){
    #pragma unroll
    for (int l = 0; l < 3; ++l)
      mx += funmap(grepM[((size_t)l*G + g)*128 + t]);
  }
  gr[256 + t] = mx;
  __syncthreads();
  float z = b1[t];
  for (int k = 0; k < 384; ++k) z += gr[k]*w1[k*128 + t];
  z = fmaxf(z, 0.f);
  float c0 = z*w2[t*2 + 0], c1 = z*w2[t*2 + 1];
  #pragma unroll
  for (int o = 32; o > 0; o >>= 1){ c0 += __shfl_xor(c0, o); c1 += __shfl_xor(c1, o); }
  __shared__ float r0s[2], r1s[2];
  if ((t & 63) == 0){ r0s[t>>6] = c0; r1s[t>>6] = c1; }
  __syncthreads();
  if (t == 0){
    float z0 = r0s[0] + r0s[1] + b2[0];
    float z1 = r1s[0] + r1s[1] + b2[1];
    float mm = fmaxf(z0, z1);
    float lse = mm + logf(expf(z0-mm) + expf(z1-mm));
    out[g*2 + 0] = z0 - lse;
    out[g*2 + 1] = z1 - lse;
  }
}

extern "C" void kernel_launch(void* const* d_in, const int* in_sizes, int n_in,
                              void* d_out, int out_size, void* d_ws, size_t ws_size,
                              hipStream_t stream) {
  const float* x     = (const float*)d_in[0];
  const int*   ei    = (const int*)d_in[1];
  const int*   batch = (const int*)d_in[2];
  const float* gamma = (const float*)d_in[3];
  const float* beta  = (const float*)d_in[4];
  const float* W0    = (const float*)d_in[5];
  const float* b0    = (const float*)d_in[6];
  const float* W1    = (const float*)d_in[7];
  const float* b1    = (const float*)d_in[8];
  const float* W2    = (const float*)d_in[9];
  const float* b2    = (const float*)d_in[10];
  const float* tar   = (const float*)d_in[11];
  const float* l1w   = (const float*)d_in[12];
  const float* l1b   = (const float*)d_in[13];
  const float* l2w   = (const float*)d_in[14];
  const float* l2b   = (const float*)d_in[15];
  float* out = (float*)d_out;

  int N = in_sizes[0] / 128;
  int E = in_sizes[1] / 2;
  int G = out_size / 2;
  const int* srcp = ei;
  const int* dstp = ei + E;

  char* wsb = (char*)d_ws;
  size_t off = 0;
  auto alloc = [&](size_t bytes)->char*{
    char* p = wsb + off; off += (bytes + 255) & ~(size_t)255; return p;
  };
  unsigned short* h = (unsigned short*)alloc((size_t)N*128*2);
  unsigned short* m = (unsigned short*)alloc((size_t)N*128*2);
  float* dinv    = (float*)alloc((size_t)N*4);
  int*   rowst   = (int*)  alloc((size_t)(N+1)*4);
  int*   csrs    = (int*)  alloc((size_t)E*4);
  unsigned* ebuf = (unsigned*)alloc((size_t)E*4);
  int*   hist2   = (int*)  alloc((size_t)NCHUNK*512*4);
  int*   offs2   = (int*)  alloc((size_t)NCHUNK*512*4);
  int*   bbase   = (int*)  alloc(513*4);
  int*   gstart  = (int*)  alloc((size_t)(G+1)*4);
  float* grepF   = (float*)alloc((size_t)(2*G)*128*4 + (size_t)(3*G)*128*4); // + grepM contiguous
  unsigned* grepM = (unsigned*)(grepF + (size_t)(2*G)*128);
  float* stats   = (float*)alloc(2*128*4);
  float* bias0p  = (float*)alloc(128*4);
  float* part    = (float*)alloc((size_t)512*256*4);
  unsigned short* Wh = (unsigned short*)alloc(3*16384*2);
  (void)ws_size;

  float* scale  = stats;
  float* shift  = stats + 128;

  int NB = (N + 255) >> 8;                 // 391 for N=100000 (<=512)
  int CH = (E + NCHUNK - 1) / NCHUNK;
  hipMemsetAsync(grepF, 0, (size_t)(5*G)*128*4, stream);  // ws+sm+3x max

  // K1: chunk histogram || BN partials
  k_hist_bn<<<NCHUNK + 512, 256, 0, stream>>>(dstp, hist2, E, NB, CH, x, part, N*32);
  // K2: offset scan || BN finalize || graph bounds
  k_scan_red_gb<<<4, 512, 0, stream>>>(hist2, offs2, bbase, NB, E,
                                       part, gamma, beta, scale, shift, N,
                                       batch, gstart, G);
  chunk_scatter<<<NCHUNK, 256, 0, stream>>>(srcp, dstp, offs2, ebuf, E, NB, CH);
  // K3: bucket sort || weight prep || bias0 prep
  k_sort_prep<<<NB + 193, 256, 0, stream>>>(ebuf, bbase, csrs, rowst, dinv, N, E, NB,
                                            W0, W1, W2, scale, Wh, b0, shift, bias0p);

  const float* bs[3] = {bias0p, b1, b2};
  int nb64 = (N + 63) / 64;
  for (int l = 0; l < 3; ++l){
    if (l == 0)
      gemm_mfma<1><<<nb64, 512, 0, stream>>>(x, nullptr, Wh, m, N);
    else
      gemm_mfma<0><<<nb64, 512, 0, stream>>>(nullptr, h, Wh + l*16384, m, N);
    if (l < 2)
      gather_ro<0><<<(N+7)/8, 256, 0, stream>>>(m, rowst, csrs, dinv, bs[l], tar + l*128,
                                                batch, h, grepF, grepM + (size_t)l*G*128, N, G);
    else
      gather_ro<1><<<(N+7)/8, 256, 0, stream>>>(m, rowst, csrs, dinv, bs[l], tar + l*128,
                                                batch, h, grepF, grepM + (size_t)l*G*128, N, G);
  }
  classify<<<G, 128, 0, stream>>>(grepF, grepM, gstart, l1w, l1b, l2w, l2b, out, G);
}

// Round 15
// 252.365 us; speedup vs baseline: 2.3398x; 2.3398x over previous
//
#include <hip/hip_runtime.h>
#include <hip/hip_bf16.h>
#include <math.h>

#define BN_EPS 1e-5f
#define NCHUNK 256

typedef __attribute__((ext_vector_type(8)))  short short8v;
typedef __attribute__((ext_vector_type(16))) float f32x16;

__device__ __forceinline__ unsigned short f2bf(float f){
  union { float f; unsigned u; } v; v.f = f;
  unsigned r = v.u + 0x7FFFu + ((v.u >> 16) & 1u);
  return (unsigned short)(r >> 16);
}
__device__ __forceinline__ float2 bfpair(unsigned u){
  union { unsigned u; float f; } lo, hi;
  lo.u = u << 16;
  hi.u = u & 0xFFFF0000u;
  return make_float2(lo.f, hi.f);
}
__device__ __forceinline__ unsigned packbf(float a, float b){
  return (unsigned)f2bf(a) | ((unsigned)f2bf(b) << 16);
}

// ========== K1: chunk_hist (blocks 0..NCHUNK-1) || bn_part (blocks NCHUNK..NCHUNK+511) ==========
__global__ __launch_bounds__(256) void k_hist_bn(const int* __restrict__ dst,
                                                 int* __restrict__ hist2, int E, int NB, int CH,
                                                 const float* __restrict__ x,
                                                 float* __restrict__ part, int total4){
  int tid = threadIdx.x;
  if (blockIdx.x < NCHUNK){
    __shared__ int lh[512];
    for (int i = tid; i < NB; i += 256) lh[i] = 0;
    __syncthreads();
    int c = blockIdx.x;
    int e0 = c*CH, e1 = min(e0 + CH, E);
    for (int e = e0 + tid; e < e1; e += 256)
      atomicAdd(&lh[dst[e] >> 8], 1);
    __syncthreads();
    for (int i = tid; i < NB; i += 256)
      hist2[c*NB + i] = lh[i];
  } else {
    const float4* x4 = (const float4*)x;
    int bb = blockIdx.x - NCHUNK;          // 0..511
    int stride = 512 * 256;
    float4 s = make_float4(0.f,0.f,0.f,0.f);
    float4 q = make_float4(0.f,0.f,0.f,0.f);
    for (int idx = bb*256 + tid; idx < total4; idx += stride){
      float4 v = x4[idx];
      s.x += v.x; s.y += v.y; s.z += v.z; s.w += v.w;
      q.x += v.x*v.x; q.y += v.y*v.y; q.z += v.z*v.z; q.w += v.w*v.w;
    }
    __shared__ float4 shs[256], shq[256];
    shs[tid] = s; shq[tid] = q;
    __syncthreads();
    if (tid < 32){
      int c4 = tid;
      float4 ts = shs[c4], tq = shq[c4];
      #pragma unroll
      for (int j = 1; j < 8; ++j){
        float4 os = shs[c4 + j*32], oq = shq[c4 + j*32];
        ts.x += os.x; ts.y += os.y; ts.z += os.z; ts.w += os.w;
        tq.x += oq.x; tq.y += oq.y; tq.z += oq.z; tq.w += oq.w;
      }
      float* pb = part + (size_t)bb * 256;
      *(float4*)(pb + c4*4)       = ts;
      *(float4*)(pb + 128 + c4*4) = tq;
    }
  }
}

// ========== K2: chunk_scan (blk 0) || bn_reduce (blk 1) || gbounds (blk 2,3) ==========
__global__ __launch_bounds__(512) void k_scan_red_gb(const int* __restrict__ hist2,
                                                     int* __restrict__ offs2,
                                                     int* __restrict__ bbase, int NB, int E,
                                                     const float* __restrict__ part,
                                                     const float* __restrict__ gamma,
                                                     const float* __restrict__ beta,
                                                     float* __restrict__ scale,
                                                     float* __restrict__ shift, int N,
                                                     const int* __restrict__ batch,
                                                     int* __restrict__ gstart, int G){
  int t = threadIdx.x;
  if (blockIdx.x == 0){
    __shared__ int tot[512];
    int b = t;
    int total = 0;
    if (b < NB){
      for (int c = 0; c < NCHUNK; c += 8){
        int h0 = hist2[(c+0)*NB + b], h1 = hist2[(c+1)*NB + b];
        int h2 = hist2[(c+2)*NB + b], h3 = hist2[(c+3)*NB + b];
        int h4 = hist2[(c+4)*NB + b], h5 = hist2[(c+5)*NB + b];
        int h6 = hist2[(c+6)*NB + b], h7 = hist2[(c+7)*NB + b];
        total += ((h0+h1)+(h2+h3)) + ((h4+h5)+(h6+h7));
      }
    }
    tot[b] = (b < NB) ? total : 0;
    __syncthreads();
    int v = tot[b];
    for (int d = 1; d < 512; d <<= 1){
      int u = (b >= d) ? tot[b-d] : 0;
      __syncthreads();
      tot[b] += u;
      __syncthreads();
    }
    if (b < NB){
      int base = tot[b] - v;
      bbase[b] = base;
      int run = base;
      for (int c = 0; c < NCHUNK; ++c){
        offs2[c*NB + b] = run;
        run += hist2[c*NB + b];
      }
    }
    if (b == 0) bbase[NB] = E;
  } else if (blockIdx.x == 1){
    if (t < 256){
      float a0=0.f,a1=0.f,a2=0.f,a3=0.f,a4=0.f,a5=0.f,a6=0.f,a7=0.f;
      for (int b = 0; b < 512; b += 8){
        a0 += part[(size_t)(b+0)*256 + t];
        a1 += part[(size_t)(b+1)*256 + t];
        a2 += part[(size_t)(b+2)*256 + t];
        a3 += part[(size_t)(b+3)*256 + t];
        a4 += part[(size_t)(b+4)*256 + t];
        a5 += part[(size_t)(b+5)*256 + t];
        a6 += part[(size_t)(b+6)*256 + t];
        a7 += part[(size_t)(b+7)*256 + t];
      }
      float acc = ((a0+a1)+(a2+a3)) + ((a4+a5)+(a6+a7));
      __shared__ float sh[256];
      sh[t] = acc;
      __syncthreads();
      if (t < 128){
        float mu  = sh[t] / (float)N;
        float var = sh[t+128] / (float)N - mu*mu;
        float sc  = gamma[t] * rsqrtf(var + BN_EPS);
        scale[t] = sc;
        shift[t] = beta[t] - mu*sc;
      }
    }
  } else {
    int g = (blockIdx.x - 2)*512 + t;
    if (g <= G){
      int lo = 0, hi = N;
      while (lo < hi){ int mid = (lo+hi)>>1; if (batch[mid] < g) lo = mid+1; else hi = mid; }
      gstart[g] = lo;
    }
  }
}

// ---- P3: scatter via LDS cursors (no global atomics) ----
__global__ __launch_bounds__(256) void chunk_scatter(const int* __restrict__ src,
                                                     const int* __restrict__ dst,
                                                     const int* __restrict__ offs2,
                                                     unsigned* __restrict__ ebuf,
                                                     int E, int NB, int CH){
  __shared__ int lcur[512];
  int c = blockIdx.x;
  for (int i = threadIdx.x; i < NB; i += 256) lcur[i] = offs2[c*NB + i];
  __syncthreads();
  int e0 = c*CH, e1 = min(e0 + CH, E);
  for (int e = e0 + threadIdx.x; e < e1; e += 256){
    int d = dst[e];
    int b = d >> 8;
    int pos = atomicAdd(&lcur[b], 1);
    ebuf[pos] = ((unsigned)(d & 255) << 24) | (unsigned)src[e];
  }
}

// ========== K3: bucket_sort (blks 0..NB-1) || prep_w (NB..NB+191) || prep_bias0 (NB+192) ==========
__global__ __launch_bounds__(256) void k_sort_prep(const unsigned* __restrict__ ebuf,
                                                   const int* __restrict__ bbase,
                                                   int* __restrict__ csrs,
                                                   int* __restrict__ rowstart,
                                                   float* __restrict__ dinv,
                                                   int N, int E, int NB,
                                                   const float* __restrict__ W0,
                                                   const float* __restrict__ W1,
                                                   const float* __restrict__ W2,
                                                   const float* __restrict__ scale,
                                                   unsigned short* __restrict__ Wh,
                                                   const float* __restrict__ b0,
                                                   const float* __restrict__ shift,
                                                   float* __restrict__ bias0p){
  int tid = threadIdx.x;
  if ((int)blockIdx.x < NB){
    int b = blockIdx.x;
    int base = bbase[b];
    int end  = bbase[b+1];
    int len  = end - base;
    __shared__ int cnt[256];
    __shared__ int pref[256];
    cnt[tid] = 0;
    __syncthreads();
    for (int i = tid; i < len; i += 256)
      atomicAdd(&cnt[ebuf[base + i] >> 24], 1);
    __syncthreads();
    int v = cnt[tid];
    pref[tid] = v;
    __syncthreads();
    for (int d = 1; d < 256; d <<= 1){
      int u = (tid >= d) ? pref[tid-d] : 0;
      __syncthreads();
      pref[tid] += u;
      __syncthreads();
    }
    int excl = pref[tid] - v;
    int node = b*256 + tid;
    if (node < N){
      rowstart[node] = base + excl;
      dinv[node] = rsqrtf((float)v + 1.0f);
    }
    cnt[tid] = excl;
    __syncthreads();
    for (int i = tid; i < len; i += 256){
      unsigned r = ebuf[base + i];
      int pos = atomicAdd(&cnt[r >> 24], 1);
      csrs[base + pos] = (int)(r & 0xFFFFFFu);
    }
    if (b == NB-1 && tid == 0) rowstart[N] = E;
  } else if ((int)blockIdx.x < NB + 192){
    int idx = (blockIdx.x - NB)*256 + tid;   // 0..49151 = 3*16384
    int l = idx >> 14, r = idx & 16383, c = r >> 7, k = r & 127;
    const float* W = (l==0) ? W0 : (l==1) ? W1 : W2;
    float v = W[k*128 + c];
    if (l == 0) v *= scale[k];
    Wh[idx] = f2bf(v);
  } else {
    __shared__ float sh[128];
    if (tid < 128) sh[tid] = shift[tid];
    __syncthreads();
    if (tid < 128){
      float s = b0[tid];
      for (int c = 0; c < 128; ++c) s += sh[c] * W0[c*128 + tid];
      bias0p[tid] = s;
    }
  }
}

// ---------------- lean MFMA GEMM: C[N,128] (bf16) = A @ W_hi ----------------
template<int CVT>
__global__ __launch_bounds__(512) void gemm_mfma(
    const float* __restrict__ A32, const unsigned short* __restrict__ A16,
    const unsigned short* __restrict__ Bh, unsigned short* __restrict__ C, int N){
  __shared__ unsigned short Ah[64*128];
  int tid = threadIdx.x;
  int r0 = blockIdx.x * 64;
  int w = tid >> 6, lane = tid & 63;
  int rt = w & 1;
  int ct = (w >> 1) * 32;
  int lrow = 32*rt + (lane & 31);
  int khalf = lane >> 5;
  int c0 = ct + (lane & 31);
  const unsigned short* bh0 = Bh + (size_t)c0*128 + khalf*8;

  short8v bhf[8];
  #pragma unroll
  for (int s = 0; s < 8; ++s) bhf[s] = *(const short8v*)(bh0 + s*16);

  if (CVT){
    #pragma unroll
    for (int it = 0; it < 4; ++it){
      int idx = tid + it*512;
      int row = idx >> 5;
      int c4  = idx & 31;
      int r = r0 + row;
      float4 av = (r < N) ? *(const float4*)(A32 + (size_t)r*128 + c4*4)
                          : make_float4(0.f,0.f,0.f,0.f);
      int byte0 = (c4*8) ^ ((row & 15) << 4);
      uint2 p = make_uint2(packbf(av.x, av.y), packbf(av.z, av.w));
      *(uint2*)((char*)Ah + row*256 + byte0) = p;
    }
  } else {
    #pragma unroll
    for (int it = 0; it < 2; ++it){
      int idx = tid + it*512;
      int row = idx >> 4;
      int c8  = idx & 15;
      int r = r0 + row;
      uint4 v = (r < N) ? *(const uint4*)(A16 + (size_t)r*128 + c8*8)
                        : make_uint4(0,0,0,0);
      int byte0 = (c8*16) ^ ((row & 15) << 4);
      *(uint4*)((char*)Ah + row*256 + byte0) = v;
    }
  }
  __syncthreads();

  f32x16 acc = {};
  const char* AhB = (const char*)Ah + lrow*256;
  int sw = (lrow & 15) << 4;
  #pragma unroll
  for (int s = 0; s < 8; ++s){
    int abyte = (s*32 + khalf*16) ^ sw;
    short8v a = *(const short8v*)(AhB + abyte);
    acc = __builtin_amdgcn_mfma_f32_32x32x16_bf16(a, bhf[s], acc, 0, 0, 0);
  }

  #pragma unroll
  for (int r = 0; r < 16; ++r){
    int row = r0 + 32*rt + (r & 3) + 8*(r >> 2) + 4*khalf;
    if (row < N) C[(size_t)row*128 + c0] = f2bf(acc[r]);
  }
}

// ---------------- fused aggregation + bias + squash + attention ----------------
__global__ __launch_bounds__(256) void gather_squash(
    const unsigned short* __restrict__ m, const int* __restrict__ rowstart,
    const int* __restrict__ csrs, const float* __restrict__ dinv,
    const float* __restrict__ bias, const float* __restrict__ tar,
    unsigned short* __restrict__ h, float* __restrict__ attn, int N){
  int node = blockIdx.x*8 + (threadIdx.x >> 5);
  if (node >= N) return;
  int lane = threadIdx.x & 31;
  const uint2* m2 = (const uint2*)m;
  float dv = dinv[node];
  float sn = dv*dv;
  uint2 sv = m2[(size_t)node*32 + lane];
  float2 p0 = bfpair(sv.x), p1 = bfpair(sv.y);
  float a0 = p0.x*sn, a1 = p0.y*sn, a2 = p1.x*sn, a3 = p1.y*sn;
  int j0 = rowstart[node], j1 = rowstart[node+1];

  for (int base = j0; base < j1; base += 32){
    int cnt = j1 - base; if (cnt > 32) cnt = 32;
    int sidx = 0; float swt = 0.f;
    if (lane < cnt){
      sidx = csrs[base + lane];
      swt  = dinv[sidx] * dv;
    }
    int t = 0;
    for (; t + 4 <= cnt; t += 4){
      int s0 = __shfl(sidx, t, 32),   s1 = __shfl(sidx, t+1, 32);
      int s2 = __shfl(sidx, t+2, 32), s3 = __shfl(sidx, t+3, 32);
      float w0 = __shfl(swt, t, 32),   w1 = __shfl(swt, t+1, 32);
      float w2 = __shfl(swt, t+2, 32), w3 = __shfl(swt, t+3, 32);
      uint2 u0 = m2[(size_t)s0*32 + lane];
      uint2 u1 = m2[(size_t)s1*32 + lane];
      uint2 u2 = m2[(size_t)s2*32 + lane];
      uint2 u3 = m2[(size_t)s3*32 + lane];
      float2 q0, q1;
      q0 = bfpair(u0.x); q1 = bfpair(u0.y);
      a0 += w0*q0.x; a1 += w0*q0.y; a2 += w0*q1.x; a3 += w0*q1.y;
      q0 = bfpair(u1.x); q1 = bfpair(u1.y);
      a0 += w1*q0.x; a1 += w1*q0.y; a2 += w1*q1.x; a3 += w1*q1.y;
      q0 = bfpair(u2.x); q1 = bfpair(u2.y);
      a0 += w2*q0.x; a1 += w2*q0.y; a2 += w2*q1.x; a3 += w2*q1.y;
      q0 = bfpair(u3.x); q1 = bfpair(u3.y);
      a0 += w3*q0.x; a1 += w3*q0.y; a2 += w3*q1.x; a3 += w3*q1.y;
    }
    if (cnt - t >= 2){
      int s0 = __shfl(sidx, t, 32), s1 = __shfl(sidx, t+1, 32);
      float w0 = __shfl(swt, t, 32), w1 = __shfl(swt, t+1, 32);
      uint2 u0 = m2[(size_t)s0*32 + lane];
      uint2 u1 = m2[(size_t)s1*32 + lane];
      float2 q0 = bfpair(u0.x), q1 = bfpair(u0.y);
      a0 += w0*q0.x; a1 += w0*q0.y; a2 += w0*q1.x; a3 += w0*q1.y;
      q0 = bfpair(u1.x); q1 = bfpair(u1.y);
      a0 += w1*q0.x; a1 += w1*q0.y; a2 += w1*q1.x; a3 += w1*q1.y;
      t += 2;
    }
    if (t < cnt){
      int s0 = __shfl(sidx, t, 32);
      float w0 = __shfl(swt, t, 32);
      uint2 u0 = m2[(size_t)s0*32 + lane];
      float2 q0 = bfpair(u0.x), q1 = bfpair(u0.y);
      a0 += w0*q0.x; a1 += w0*q0.y; a2 += w0*q1.x; a3 += w0*q1.y;
    }
  }

  float4 bv = ((const float4*)bias)[lane];
  a0 += bv.x; a1 += bv.y; a2 += bv.z; a3 += bv.w;
  float n2 = a0*a0 + a1*a1 + a2*a2 + a3*a3;
  #pragma unroll
  for (int o = 16; o > 0; o >>= 1) n2 += __shfl_xor(n2, o);
  float sc = (n2/(1.f+n2)) * rsqrtf(n2 + 1e-12f);
  float h0 = a0*sc, h1 = a1*sc, h2 = a2*sc, h3 = a3*sc;
  ((uint2*)(h + (size_t)node*128))[lane] = make_uint2(packbf(h0,h1), packbf(h2,h3));
  float4 tv = ((const float4*)tar)[lane];
  float at = h0*tv.x + h1*tv.y + h2*tv.z + h3*tv.w;
  #pragma unroll
  for (int o = 16; o > 0; o >>= 1) at += __shfl_xor(at, o);
  if (lane == 0) attn[node] = at;
}

// ---------------- per-graph readout (wsum / mean / max), accumulated ----------------
__global__ __launch_bounds__(1024) void readout(const unsigned short* __restrict__ h,
                                                const float* __restrict__ attn,
                                                const int* __restrict__ gstart,
                                                float* __restrict__ grep){
  int g = blockIdx.x;
  int t   = threadIdx.x & 63;
  int grp = threadIdx.x >> 6;
  int a = gstart[g], b = gstart[g+1];
  float wsx = 0.f, wsy = 0.f, smx_ = 0.f, smy_ = 0.f;
  float mxx = -INFINITY, mxy = -INFINITY;
  for (int n = a + grp; n < b; n += 16){
    unsigned u = ((const unsigned*)(h + (size_t)n*128))[t];
    float2 v = bfpair(u);
    float at = attn[n];
    wsx += at*v.x; wsy += at*v.y;
    smx_ += v.x;  smy_ += v.y;
    mxx = fmaxf(mxx, v.x); mxy = fmaxf(mxy, v.y);
  }
  __shared__ float2 sws[16][64], ssm[16][64], smx[16][64];
  sws[grp][t] = make_float2(wsx, wsy);
  ssm[grp][t] = make_float2(smx_, smy_);
  smx[grp][t] = make_float2(mxx, mxy);
  __syncthreads();
  if (grp == 0){
    #pragma unroll
    for (int j = 1; j < 16; ++j){
      float2 ow = sws[j][t], os = ssm[j][t], om = smx[j][t];
      wsx += ow.x; wsy += ow.y;
      smx_ += os.x; smy_ += os.y;
      mxx = fmaxf(mxx, om.x); mxy = fmaxf(mxy, om.y);
    }
    int cnt = b - a;
    float inv = 1.f / fmaxf((float)cnt, 1.f);
    if (cnt == 0){ mxx = 0.f; mxy = 0.f; }
    grep[(size_t)g*384 + t*2]           += wsx;
    grep[(size_t)g*384 + t*2 + 1]       += wsy;
    grep[(size_t)g*384 + 128 + t*2]     += smx_*inv;
    grep[(size_t)g*384 + 128 + t*2 + 1] += smy_*inv;
    grep[(size_t)g*384 + 256 + t*2]     += mxx;
    grep[(size_t)g*384 + 256 + t*2 + 1] += mxy;
  }
}

// ---------------- classifier head + log_softmax ----------------
__global__ __launch_bounds__(128) void classify(const float* __restrict__ grep,
                                                const float* __restrict__ w1, const float* __restrict__ b1,
                                                const float* __restrict__ w2, const float* __restrict__ b2,
                                                float* __restrict__ out){
  int g = blockIdx.x, t = threadIdx.x;
  __shared__ float gr[384];
  for (int i = t; i < 384; i += 128) gr[i] = grep[(size_t)g*384 + i];
  __syncthreads();
  float z = b1[t];
  for (int k = 0; k < 384; ++k) z += gr[k]*w1[k*128 + t];
  z = fmaxf(z, 0.f);
  float c0 = z*w2[t*2 + 0], c1 = z*w2[t*2 + 1];
  #pragma unroll
  for (int o = 32; o > 0; o >>= 1){ c0 += __shfl_xor(c0, o); c1 += __shfl_xor(c1, o); }
  __shared__ float r0s[2], r1s[2];
  if ((t & 63) == 0){ r0s[t>>6] = c0; r1s[t>>6] = c1; }
  __syncthreads();
  if (t == 0){
    float z0 = r0s[0] + r0s[1] + b2[0];
    float z1 = r1s[0] + r1s[1] + b2[1];
    float mm = fmaxf(z0, z1);
    float lse = mm + logf(expf(z0-mm) + expf(z1-mm));
    out[g*2 + 0] = z0 - lse;
    out[g*2 + 1] = z1 - lse;
  }
}

extern "C" void kernel_launch(void* const* d_in, const int* in_sizes, int n_in,
                              void* d_out, int out_size, void* d_ws, size_t ws_size,
                              hipStream_t stream) {
  const float* x     = (const float*)d_in[0];
  const int*   ei    = (const int*)d_in[1];
  const int*   batch = (const int*)d_in[2];
  const float* gamma = (const float*)d_in[3];
  const float* beta  = (const float*)d_in[4];
  const float* W0    = (const float*)d_in[5];
  const float* b0    = (const float*)d_in[6];
  const float* W1    = (const float*)d_in[7];
  const float* b1    = (const float*)d_in[8];
  const float* W2    = (const float*)d_in[9];
  const float* b2    = (const float*)d_in[10];
  const float* tar   = (const float*)d_in[11];
  const float* l1w   = (const float*)d_in[12];
  const float* l1b   = (const float*)d_in[13];
  const float* l2w   = (const float*)d_in[14];
  const float* l2b   = (const float*)d_in[15];
  float* out = (float*)d_out;

  int N = in_sizes[0] / 128;
  int E = in_sizes[1] / 2;
  int G = out_size / 2;
  const int* srcp = ei;
  const int* dstp = ei + E;

  char* wsb = (char*)d_ws;
  size_t off = 0;
  auto alloc = [&](size_t bytes)->char*{
    char* p = wsb + off; off += (bytes + 255) & ~(size_t)255; return p;
  };
  unsigned short* h = (unsigned short*)alloc((size_t)N*128*2);
  unsigned short* m = (unsigned short*)alloc((size_t)N*128*2);
  float* attn    = (float*)alloc((size_t)N*4);
  float* dinv    = (float*)alloc((size_t)N*4);
  int*   rowst   = (int*)  alloc((size_t)(N+1)*4);
  int*   csrs    = (int*)  alloc((size_t)E*4);
  unsigned* ebuf = (unsigned*)alloc((size_t)E*4);
  int*   hist2   = (int*)  alloc((size_t)NCHUNK*512*4);
  int*   offs2   = (int*)  alloc((size_t)NCHUNK*512*4);
  int*   bbase   = (int*)  alloc(513*4);
  int*   gstart  = (int*)  alloc((size_t)(G+1)*4);
  float* grep    = (float*)alloc((size_t)G*384*4);
  float* stats   = (float*)alloc(2*128*4);
  float* bias0p  = (float*)alloc(128*4);
  float* part    = (float*)alloc((size_t)512*256*4);
  unsigned short* Wh = (unsigned short*)alloc(3*16384*2);
  (void)ws_size;

  float* scale  = stats;
  float* shift  = stats + 128;

  int NB = (N + 255) >> 8;                 // 391 for N=100000 (<=512)
  int CH = (E + NCHUNK - 1) / NCHUNK;
  hipMemsetAsync(grep, 0, (size_t)G*384*4, stream);

  // K1: chunk histogram || BN partials
  k_hist_bn<<<NCHUNK + 512, 256, 0, stream>>>(dstp, hist2, E, NB, CH, x, part, N*32);
  // K2: offset scan || BN finalize || graph bounds
  k_scan_red_gb<<<4, 512, 0, stream>>>(hist2, offs2, bbase, NB, E,
                                       part, gamma, beta, scale, shift, N,
                                       batch, gstart, G);
  chunk_scatter<<<NCHUNK, 256, 0, stream>>>(srcp, dstp, offs2, ebuf, E, NB, CH);
  // K3: bucket sort || weight prep || bias0 prep
  k_sort_prep<<<NB + 193, 256, 0, stream>>>(ebuf, bbase, csrs, rowst, dinv, N, E, NB,
                                            W0, W1, W2, scale, Wh, b0, shift, bias0p);

  const float* bs[3] = {bias0p, b1, b2};
  int nb64 = (N + 63) / 64;
  for (int l = 0; l < 3; ++l){
    if (l == 0)
      gemm_mfma<1><<<nb64, 512, 0, stream>>>(x, nullptr, Wh, m, N);
    else
      gemm_mfma<0><<<nb64, 512, 0, stream>>>(nullptr, h, Wh + l*16384, m, N);
    gather_squash<<<(N+7)/8, 256, 0, stream>>>(m, rowst, csrs, dinv, bs[l], tar + l*128, h, attn, N);
    readout<<<G, 1024, 0, stream>>>(h, attn, gstart, grep);
  }
  classify<<<G, 128, 0, stream>>>(grep, l1w, l1b, l2w, l2b, out);
}

// Round 16
// 242.417 us; speedup vs baseline: 2.4358x; 1.0410x over previous
//
#include <hip/hip_runtime.h>
#include <hip/hip_bf16.h>
#include <math.h>

#define BN_EPS 1e-5f
#define NCHUNK 256

typedef __attribute__((ext_vector_type(8)))  short short8v;
typedef __attribute__((ext_vector_type(16))) float f32x16;

__device__ __forceinline__ unsigned short f2bf(float f){
  union { float f; unsigned u; } v; v.f = f;
  unsigned r = v.u + 0x7FFFu + ((v.u >> 16) & 1u);
  return (unsigned short)(r >> 16);
}
__device__ __forceinline__ float2 bfpair(unsigned u){
  union { unsigned u; float f; } lo, hi;
  lo.u = u << 16;
  hi.u = u & 0xFFFF0000u;
  return make_float2(lo.f, hi.f);
}
__device__ __forceinline__ unsigned packbf(float a, float b){
  return (unsigned)f2bf(a) | ((unsigned)f2bf(b) << 16);
}

// ================= device bodies (shared across packed kernels) =================

// ---- lean MFMA GEMM body: C[N,128] (bf16) = A @ W_hi. 512 threads, 16 KB LDS ----
template<int CVT>
__device__ __forceinline__ void gemm_body(int bid, int tid,
    const float* __restrict__ A32, const unsigned short* __restrict__ A16,
    const unsigned short* __restrict__ Bh, unsigned short* __restrict__ C, int N,
    unsigned short* Ah){
  int r0 = bid * 64;
  int w = tid >> 6, lane = tid & 63;
  int rt = w & 1;
  int ct = (w >> 1) * 32;
  int lrow = 32*rt + (lane & 31);
  int khalf = lane >> 5;
  int c0 = ct + (lane & 31);
  const unsigned short* bh0 = Bh + (size_t)c0*128 + khalf*8;

  short8v bhf[8];
  #pragma unroll
  for (int s = 0; s < 8; ++s) bhf[s] = *(const short8v*)(bh0 + s*16);

  if (CVT){
    #pragma unroll
    for (int it = 0; it < 4; ++it){
      int idx = tid + it*512;
      int row = idx >> 5;
      int c4  = idx & 31;
      int r = r0 + row;
      float4 av = (r < N) ? *(const float4*)(A32 + (size_t)r*128 + c4*4)
                          : make_float4(0.f,0.f,0.f,0.f);
      int byte0 = (c4*8) ^ ((row & 15) << 4);
      uint2 p = make_uint2(packbf(av.x, av.y), packbf(av.z, av.w));
      *(uint2*)((char*)Ah + row*256 + byte0) = p;
    }
  } else {
    #pragma unroll
    for (int it = 0; it < 2; ++it){
      int idx = tid + it*512;
      int row = idx >> 4;
      int c8  = idx & 15;
      int r = r0 + row;
      uint4 v = (r < N) ? *(const uint4*)(A16 + (size_t)r*128 + c8*8)
                        : make_uint4(0,0,0,0);
      int byte0 = (c8*16) ^ ((row & 15) << 4);
      *(uint4*)((char*)Ah + row*256 + byte0) = v;
    }
  }
  __syncthreads();

  f32x16 acc = {};
  const char* AhB = (const char*)Ah + lrow*256;
  int sw = (lrow & 15) << 4;
  #pragma unroll
  for (int s = 0; s < 8; ++s){
    int abyte = (s*32 + khalf*16) ^ sw;
    short8v a = *(const short8v*)(AhB + abyte);
    acc = __builtin_amdgcn_mfma_f32_32x32x16_bf16(a, bhf[s], acc, 0, 0, 0);
  }

  #pragma unroll
  for (int r = 0; r < 16; ++r){
    int row = r0 + 32*rt + (r & 3) + 8*(r >> 2) + 4*khalf;
    if (row < N) C[(size_t)row*128 + c0] = f2bf(acc[r]);
  }
}

// ---- per-graph readout body: 512 threads (8 node-groups x 64 feat-pairs), 12 KB LDS ----
__device__ __forceinline__ void readout_body(int g, int tid,
    const unsigned short* __restrict__ h, const float* __restrict__ attn,
    const int* __restrict__ gstart, float* __restrict__ grep, char* smem){
  float2* sws = (float2*)smem;            // 8*64
  float2* ssm = sws + 8*64;
  float2* smx = ssm + 8*64;
  int t = tid & 63, grp = tid >> 6;       // 8 groups
  int a = gstart[g], b = gstart[g+1];
  float wsx = 0.f, wsy = 0.f, smx_ = 0.f, smy_ = 0.f;
  float mxx = -INFINITY, mxy = -INFINITY;
  for (int n = a + grp; n < b; n += 8){
    unsigned u = ((const unsigned*)(h + (size_t)n*128))[t];
    float2 v = bfpair(u);
    float at = attn[n];
    wsx += at*v.x; wsy += at*v.y;
    smx_ += v.x;  smy_ += v.y;
    mxx = fmaxf(mxx, v.x); mxy = fmaxf(mxy, v.y);
  }
  sws[grp*64 + t] = make_float2(wsx, wsy);
  ssm[grp*64 + t] = make_float2(smx_, smy_);
  smx[grp*64 + t] = make_float2(mxx, mxy);
  __syncthreads();
  if (grp == 0){
    #pragma unroll
    for (int j = 1; j < 8; ++j){
      float2 ow = sws[j*64 + t], os = ssm[j*64 + t], om = smx[j*64 + t];
      wsx += ow.x; wsy += ow.y;
      smx_ += os.x; smy_ += os.y;
      mxx = fmaxf(mxx, om.x); mxy = fmaxf(mxy, om.y);
    }
    int cnt = b - a;
    float inv = 1.f / fmaxf((float)cnt, 1.f);
    if (cnt == 0){ mxx = 0.f; mxy = 0.f; }
    grep[(size_t)g*384 + t*2]           += wsx;
    grep[(size_t)g*384 + t*2 + 1]       += wsy;
    grep[(size_t)g*384 + 128 + t*2]     += smx_*inv;
    grep[(size_t)g*384 + 128 + t*2 + 1] += smy_*inv;
    grep[(size_t)g*384 + 256 + t*2]     += mxx;
    grep[(size_t)g*384 + 256 + t*2 + 1] += mxy;
  }
}

// ---- bucket counting-sort body: 512 threads (first 256 active), 2 KB LDS ----
__device__ __forceinline__ void sort_body(int b, int tid,
    const unsigned* __restrict__ ebuf, const int* __restrict__ bbase,
    int* __restrict__ csrs, int* __restrict__ rowstart, float* __restrict__ dinv,
    int N, int E, int NB, int* cnt, int* pref){
  bool act = tid < 256;
  int base = bbase[b], end = bbase[b+1], len = end - base;
  if (act) cnt[tid] = 0;
  __syncthreads();
  if (act) for (int i = tid; i < len; i += 256)
    atomicAdd(&cnt[ebuf[base + i] >> 24], 1);
  __syncthreads();
  int v = 0;
  if (act){ v = cnt[tid]; pref[tid] = v; }
  __syncthreads();
  for (int d = 1; d < 256; d <<= 1){
    int u = 0;
    if (act && tid >= d) u = pref[tid-d];
    __syncthreads();
    if (act) pref[tid] += u;
    __syncthreads();
  }
  if (act){
    int excl = pref[tid] - v;
    int node = b*256 + tid;
    if (node < N){
      rowstart[node] = base + excl;
      dinv[node] = rsqrtf((float)v + 1.0f);
    }
    cnt[tid] = excl;
  }
  __syncthreads();
  if (act) for (int i = tid; i < len; i += 256){
    unsigned r = ebuf[base + i];
    int pos = atomicAdd(&cnt[r >> 24], 1);
    csrs[base + pos] = (int)(r & 0xFFFFFFu);
  }
  if (b == NB-1 && tid == 0) rowstart[N] = E;
}

// ================= packed kernels =================

// K1: chunk_hist (0..NCHUNK-1) || bn_part (NCHUNK..NCHUNK+511) || zero grep (+24)
__global__ __launch_bounds__(256) void k_pre1(const int* __restrict__ dst,
                                              int* __restrict__ hist2, int E, int NB, int CH,
                                              const float* __restrict__ x,
                                              float* __restrict__ part, int total4,
                                              float* __restrict__ grep, int zt4){
  int tid = threadIdx.x;
  if (blockIdx.x < NCHUNK){
    __shared__ int lh[512];
    for (int i = tid; i < NB; i += 256) lh[i] = 0;
    __syncthreads();
    int c = blockIdx.x;
    int e0 = c*CH, e1 = min(e0 + CH, E);
    for (int e = e0 + tid; e < e1; e += 256)
      atomicAdd(&lh[dst[e] >> 8], 1);
    __syncthreads();
    for (int i = tid; i < NB; i += 256)
      hist2[c*NB + i] = lh[i];
  } else if (blockIdx.x < NCHUNK + 512){
    const float4* x4 = (const float4*)x;
    int bb = blockIdx.x - NCHUNK;
    int stride = 512 * 256;
    float4 s = make_float4(0.f,0.f,0.f,0.f);
    float4 q = make_float4(0.f,0.f,0.f,0.f);
    for (int idx = bb*256 + tid; idx < total4; idx += stride){
      float4 v = x4[idx];
      s.x += v.x; s.y += v.y; s.z += v.z; s.w += v.w;
      q.x += v.x*v.x; q.y += v.y*v.y; q.z += v.z*v.z; q.w += v.w*v.w;
    }
    __shared__ float4 shs[256], shq[256];
    shs[tid] = s; shq[tid] = q;
    __syncthreads();
    if (tid < 32){
      int c4 = tid;
      float4 ts = shs[c4], tq = shq[c4];
      #pragma unroll
      for (int j = 1; j < 8; ++j){
        float4 os = shs[c4 + j*32], oq = shq[c4 + j*32];
        ts.x += os.x; ts.y += os.y; ts.z += os.z; ts.w += os.w;
        tq.x += oq.x; tq.y += oq.y; tq.z += oq.z; tq.w += oq.w;
      }
      float* pb = part + (size_t)bb * 256;
      *(float4*)(pb + c4*4)       = ts;
      *(float4*)(pb + 128 + c4*4) = tq;
    }
  } else {
    float4* g4 = (float4*)grep;
    int bb = blockIdx.x - NCHUNK - 512;
    int stride = 24 * 256;
    float4 z = make_float4(0.f,0.f,0.f,0.f);
    for (int idx = bb*256 + tid; idx < zt4; idx += stride) g4[idx] = z;
  }
}

// K2: chunk_scan (blk 0) || bn_reduce (blk 1) || gbounds (blk 2,3)
__global__ __launch_bounds__(512) void k_pre2(const int* __restrict__ hist2,
                                              int* __restrict__ offs2,
                                              int* __restrict__ bbase, int NB, int E,
                                              const float* __restrict__ part,
                                              const float* __restrict__ gamma,
                                              const float* __restrict__ beta,
                                              float* __restrict__ scale,
                                              float* __restrict__ shift, int N,
                                              const int* __restrict__ batch,
                                              int* __restrict__ gstart, int G){
  int t = threadIdx.x;
  if (blockIdx.x == 0){
    __shared__ int tot[512];
    int b = t;
    int total = 0;
    if (b < NB){
      for (int c = 0; c < NCHUNK; c += 8){
        int h0 = hist2[(c+0)*NB + b], h1 = hist2[(c+1)*NB + b];
        int h2 = hist2[(c+2)*NB + b], h3 = hist2[(c+3)*NB + b];
        int h4 = hist2[(c+4)*NB + b], h5 = hist2[(c+5)*NB + b];
        int h6 = hist2[(c+6)*NB + b], h7 = hist2[(c+7)*NB + b];
        total += ((h0+h1)+(h2+h3)) + ((h4+h5)+(h6+h7));
      }
    }
    tot[b] = (b < NB) ? total : 0;
    __syncthreads();
    int v = tot[b];
    for (int d = 1; d < 512; d <<= 1){
      int u = (b >= d) ? tot[b-d] : 0;
      __syncthreads();
      tot[b] += u;
      __syncthreads();
    }
    if (b < NB){
      int base = tot[b] - v;
      bbase[b] = base;
      int run = base;
      for (int c = 0; c < NCHUNK; ++c){
        offs2[c*NB + b] = run;
        run += hist2[c*NB + b];
      }
    }
    if (b == 0) bbase[NB] = E;
  } else if (blockIdx.x == 1){
    if (t < 256){
      float a0=0.f,a1=0.f,a2=0.f,a3=0.f,a4=0.f,a5=0.f,a6=0.f,a7=0.f;
      for (int b = 0; b < 512; b += 8){
        a0 += part[(size_t)(b+0)*256 + t];
        a1 += part[(size_t)(b+1)*256 + t];
        a2 += part[(size_t)(b+2)*256 + t];
        a3 += part[(size_t)(b+3)*256 + t];
        a4 += part[(size_t)(b+4)*256 + t];
        a5 += part[(size_t)(b+5)*256 + t];
        a6 += part[(size_t)(b+6)*256 + t];
        a7 += part[(size_t)(b+7)*256 + t];
      }
      float acc = ((a0+a1)+(a2+a3)) + ((a4+a5)+(a6+a7));
      __shared__ float sh[256];
      sh[t] = acc;
      __syncthreads();
      if (t < 128){
        float mu  = sh[t] / (float)N;
        float var = sh[t+128] / (float)N - mu*mu;
        float sc  = gamma[t] * rsqrtf(var + BN_EPS);
        scale[t] = sc;
        shift[t] = beta[t] - mu*sc;
      }
    }
  } else {
    int g = (blockIdx.x - 2)*512 + t;
    if (g <= G){
      int lo = 0, hi = N;
      while (lo < hi){ int mid = (lo+hi)>>1; if (batch[mid] < g) lo = mid+1; else hi = mid; }
      gstart[g] = lo;
    }
  }
}

// K3: chunk_scatter (0..NCHUNK-1) || prep_w (NCHUNK..NCHUNK+191)
__global__ __launch_bounds__(256) void k_pre3(const int* __restrict__ src,
                                              const int* __restrict__ dst,
                                              const int* __restrict__ offs2,
                                              unsigned* __restrict__ ebuf,
                                              int E, int NB, int CH,
                                              const float* __restrict__ W0,
                                              const float* __restrict__ W1,
                                              const float* __restrict__ W2,
                                              const float* __restrict__ scale,
                                              unsigned short* __restrict__ Wh){
  int tid = threadIdx.x;
  if (blockIdx.x < NCHUNK){
    __shared__ int lcur[512];
    int c = blockIdx.x;
    for (int i = tid; i < NB; i += 256) lcur[i] = offs2[c*NB + i];
    __syncthreads();
    int e0 = c*CH, e1 = min(e0 + CH, E);
    for (int e = e0 + tid; e < e1; e += 256){
      int d = dst[e];
      int b = d >> 8;
      int pos = atomicAdd(&lcur[b], 1);
      ebuf[pos] = ((unsigned)(d & 255) << 24) | (unsigned)src[e];
    }
  } else {
    int idx = (blockIdx.x - NCHUNK)*256 + tid;   // 0..49151
    int l = idx >> 14, r = idx & 16383, c = r >> 7, k = r & 127;
    const float* W = (l==0) ? W0 : (l==1) ? W1 : W2;
    float v = W[k*128 + c];
    if (l == 0) v *= scale[k];
    Wh[idx] = f2bf(v);
  }
}

// K4: gemm0 (0..nb64-1) || bucket_sort (nb64..nb64+NB-1) || prep_bias0 (last)
__global__ __launch_bounds__(512) void k_sort_gemm0(const unsigned* __restrict__ ebuf,
                                                    const int* __restrict__ bbase,
                                                    int* __restrict__ csrs,
                                                    int* __restrict__ rowstart,
                                                    float* __restrict__ dinv,
                                                    int N, int E, int NB, int nb64,
                                                    const float* __restrict__ b0,
                                                    const float* __restrict__ shift,
                                                    const float* __restrict__ W0,
                                                    float* __restrict__ bias0p,
                                                    const float* __restrict__ x,
                                                    const unsigned short* __restrict__ Wh,
                                                    unsigned short* __restrict__ m){
  __shared__ float4 smem4[1024];  // 16 KB
  int tid = threadIdx.x;
  if ((int)blockIdx.x < nb64){
    gemm_body<1>(blockIdx.x, tid, x, nullptr, Wh, m, N, (unsigned short*)smem4);
  } else if ((int)blockIdx.x < nb64 + NB){
    int* cnt = (int*)smem4;
    int* pref = cnt + 256;
    sort_body(blockIdx.x - nb64, tid, ebuf, bbase, csrs, rowstart, dinv, N, E, NB, cnt, pref);
  } else {
    float* sh = (float*)smem4;
    if (tid < 128) sh[tid] = shift[tid];
    __syncthreads();
    if (tid < 128){
      float s = b0[tid];
      for (int c = 0; c < 128; ++c) s += sh[c] * W0[c*128 + tid];
      bias0p[tid] = s;
    }
  }
}

// K_ro_gemm: gemm (0..nb64-1, CVT=0 from bf16 h) || readout (nb64..nb64+G-1).
// nb64=0 -> pure readout.
__global__ __launch_bounds__(512) void k_ro_gemm(const unsigned short* __restrict__ h,
                                                 const float* __restrict__ attn,
                                                 const int* __restrict__ gstart,
                                                 float* __restrict__ grep,
                                                 const unsigned short* __restrict__ Bh,
                                                 unsigned short* __restrict__ m,
                                                 int N, int nb64){
  __shared__ float4 smem4[1024];
  if ((int)blockIdx.x < nb64){
    gemm_body<0>(blockIdx.x, threadIdx.x, nullptr, h, Bh, m, N, (unsigned short*)smem4);
  } else {
    readout_body(blockIdx.x - nb64, threadIdx.x, h, attn, gstart, grep, (char*)smem4);
  }
}

// ---------------- fused aggregation + bias + squash + attention ----------------
__global__ __launch_bounds__(256) void gather_squash(
    const unsigned short* __restrict__ m, const int* __restrict__ rowstart,
    const int* __restrict__ csrs, const float* __restrict__ dinv,
    const float* __restrict__ bias, const float* __restrict__ tar,
    unsigned short* __restrict__ h, float* __restrict__ attn, int N){
  int node = blockIdx.x*8 + (threadIdx.x >> 5);
  if (node >= N) return;
  int lane = threadIdx.x & 31;
  const uint2* m2 = (const uint2*)m;
  float dv = dinv[node];
  float sn = dv*dv;
  uint2 sv = m2[(size_t)node*32 + lane];
  float2 p0 = bfpair(sv.x), p1 = bfpair(sv.y);
  float a0 = p0.x*sn, a1 = p0.y*sn, a2 = p1.x*sn, a3 = p1.y*sn;
  int j0 = rowstart[node], j1 = rowstart[node+1];

  for (int base = j0; base < j1; base += 32){
    int cnt = j1 - base; if (cnt > 32) cnt = 32;
    int sidx = 0; float swt = 0.f;
    if (lane < cnt){
      sidx = csrs[base + lane];
      swt  = dinv[sidx] * dv;
    }
    int t = 0;
    for (; t + 4 <= cnt; t += 4){
      int s0 = __shfl(sidx, t, 32),   s1 = __shfl(sidx, t+1, 32);
      int s2 = __shfl(sidx, t+2, 32), s3 = __shfl(sidx, t+3, 32);
      float w0 = __shfl(swt, t, 32),   w1 = __shfl(swt, t+1, 32);
      float w2 = __shfl(swt, t+2, 32), w3 = __shfl(swt, t+3, 32);
      uint2 u0 = m2[(size_t)s0*32 + lane];
      uint2 u1 = m2[(size_t)s1*32 + lane];
      uint2 u2 = m2[(size_t)s2*32 + lane];
      uint2 u3 = m2[(size_t)s3*32 + lane];
      float2 q0, q1;
      q0 = bfpair(u0.x); q1 = bfpair(u0.y);
      a0 += w0*q0.x; a1 += w0*q0.y; a2 += w0*q1.x; a3 += w0*q1.y;
      q0 = bfpair(u1.x); q1 = bfpair(u1.y);
      a0 += w1*q0.x; a1 += w1*q0.y; a2 += w1*q1.x; a3 += w1*q1.y;
      q0 = bfpair(u2.x); q1 = bfpair(u2.y);
      a0 += w2*q0.x; a1 += w2*q0.y; a2 += w2*q1.x; a3 += w2*q1.y;
      q0 = bfpair(u3.x); q1 = bfpair(u3.y);
      a0 += w3*q0.x; a1 += w3*q0.y; a2 += w3*q1.x; a3 += w3*q1.y;
    }
    if (cnt - t >= 2){
      int s0 = __shfl(sidx, t, 32), s1 = __shfl(sidx, t+1, 32);
      float w0 = __shfl(swt, t, 32), w1 = __shfl(swt, t+1, 32);
      uint2 u0 = m2[(size_t)s0*32 + lane];
      uint2 u1 = m2[(size_t)s1*32 + lane];
      float2 q0 = bfpair(u0.x), q1 = bfpair(u0.y);
      a0 += w0*q0.x; a1 += w0*q0.y; a2 += w0*q1.x; a3 += w0*q1.y;
      q0 = bfpair(u1.x); q1 = bfpair(u1.y);
      a0 += w1*q0.x; a1 += w1*q0.y; a2 += w1*q1.x; a3 += w1*q1.y;
      t += 2;
    }
    if (t < cnt){
      int s0 = __shfl(sidx, t, 32);
      float w0 = __shfl(swt, t, 32);
      uint2 u0 = m2[(size_t)s0*32 + lane];
      float2 q0 = bfpair(u0.x), q1 = bfpair(u0.y);
      a0 += w0*q0.x; a1 += w0*q0.y; a2 += w0*q1.x; a3 += w0*q1.y;
    }
  }

  float4 bv = ((const float4*)bias)[lane];
  a0 += bv.x; a1 += bv.y; a2 += bv.z; a3 += bv.w;
  float n2 = a0*a0 + a1*a1 + a2*a2 + a3*a3;
  #pragma unroll
  for (int o = 16; o > 0; o >>= 1) n2 += __shfl_xor(n2, o);
  float sc = (n2/(1.f+n2)) * rsqrtf(n2 + 1e-12f);
  float h0 = a0*sc, h1 = a1*sc, h2 = a2*sc, h3 = a3*sc;
  ((uint2*)(h + (size_t)node*128))[lane] = make_uint2(packbf(h0,h1), packbf(h2,h3));
  float4 tv = ((const float4*)tar)[lane];
  float at = h0*tv.x + h1*tv.y + h2*tv.z + h3*tv.w;
  #pragma unroll
  for (int o = 16; o > 0; o >>= 1) at += __shfl_xor(at, o);
  if (lane == 0) attn[node] = at;
}

// ---------------- classifier head + log_softmax ----------------
__global__ __launch_bounds__(128) void classify(const float* __restrict__ grep,
                                                const float* __restrict__ w1, const float* __restrict__ b1,
                                                const float* __restrict__ w2, const float* __restrict__ b2,
                                                float* __restrict__ out){
  int g = blockIdx.x, t = threadIdx.x;
  __shared__ float gr[384];
  for (int i = t; i < 384; i += 128) gr[i] = grep[(size_t)g*384 + i];
  __syncthreads();
  float z = b1[t];
  for (int k = 0; k < 384; ++k) z += gr[k]*w1[k*128 + t];
  z = fmaxf(z, 0.f);
  float c0 = z*w2[t*2 + 0], c1 = z*w2[t*2 + 1];
  #pragma unroll
  for (int o = 32; o > 0; o >>= 1){ c0 += __shfl_xor(c0, o); c1 += __shfl_xor(c1, o); }
  __shared__ float r0s[2], r1s[2];
  if ((t & 63) == 0){ r0s[t>>6] = c0; r1s[t>>6] = c1; }
  __syncthreads();
  if (t == 0){
    float z0 = r0s[0] + r0s[1] + b2[0];
    float z1 = r1s[0] + r1s[1] + b2[1];
    float mm = fmaxf(z0, z1);
    float lse = mm + logf(expf(z0-mm) + expf(z1-mm));
    out[g*2 + 0] = z0 - lse;
    out[g*2 + 1] = z1 - lse;
  }
}

extern "C" void kernel_launch(void* const* d_in, const int* in_sizes, int n_in,
                              void* d_out, int out_size, void* d_ws, size_t ws_size,
                              hipStream_t stream) {
  const float* x     = (const float*)d_in[0];
  const int*   ei    = (const int*)d_in[1];
  const int*   batch = (const int*)d_in[2];
  const float* gamma = (const float*)d_in[3];
  const float* beta  = (const float*)d_in[4];
  const float* W0    = (const float*)d_in[5];
  const float* b0    = (const float*)d_in[6];
  const float* W1    = (const float*)d_in[7];
  const float* b1    = (const float*)d_in[8];
  const float* W2    = (const float*)d_in[9];
  const float* b2    = (const float*)d_in[10];
  const float* tar   = (const float*)d_in[11];
  const float* l1w   = (const float*)d_in[12];
  const float* l1b   = (const float*)d_in[13];
  const float* l2w   = (const float*)d_in[14];
  const float* l2b   = (const float*)d_in[15];
  float* out = (float*)d_out;

  int N = in_sizes[0] / 128;
  int E = in_sizes[1] / 2;
  int G = out_size / 2;
  const int* srcp = ei;
  const int* dstp = ei + E;

  char* wsb = (char*)d_ws;
  size_t off = 0;
  auto alloc = [&](size_t bytes)->char*{
    char* p = wsb + off; off += (bytes + 255) & ~(size_t)255; return p;
  };
  unsigned short* h = (unsigned short*)alloc((size_t)N*128*2);
  unsigned short* m = (unsigned short*)alloc((size_t)N*128*2);
  float* attn    = (float*)alloc((size_t)N*4);
  float* dinv    = (float*)alloc((size_t)N*4);
  int*   rowst   = (int*)  alloc((size_t)(N+1)*4);
  int*   csrs    = (int*)  alloc((size_t)E*4);
  unsigned* ebuf = (unsigned*)alloc((size_t)E*4);
  int*   hist2   = (int*)  alloc((size_t)NCHUNK*512*4);
  int*   offs2   = (int*)  alloc((size_t)NCHUNK*512*4);
  int*   bbase   = (int*)  alloc(513*4);
  int*   gstart  = (int*)  alloc((size_t)(G+1)*4);
  float* grep    = (float*)alloc((size_t)G*384*4);
  float* stats   = (float*)alloc(2*128*4);
  float* bias0p  = (float*)alloc(128*4);
  float* part    = (float*)alloc((size_t)512*256*4);
  unsigned short* Wh = (unsigned short*)alloc(3*16384*2);
  (void)ws_size;

  float* scale  = stats;
  float* shift  = stats + 128;

  int NB = (N + 255) >> 8;                 // 391 for N=100000 (<=512)
  int CH = (E + NCHUNK - 1) / NCHUNK;
  int nb64 = (N + 63) / 64;
  int zt4 = (G*384) / 4;                   // grep float4 count

  // K1: chunk histogram || BN partials || zero grep
  k_pre1<<<NCHUNK + 512 + 24, 256, 0, stream>>>(dstp, hist2, E, NB, CH, x, part, N*32, grep, zt4);
  // K2: offset scan || BN finalize || graph bounds
  k_pre2<<<4, 512, 0, stream>>>(hist2, offs2, bbase, NB, E,
                                part, gamma, beta, scale, shift, N, batch, gstart, G);
  // K3: edge scatter || weight prep (BN-scaled W0)
  k_pre3<<<NCHUNK + 192, 256, 0, stream>>>(srcp, dstp, offs2, ebuf, E, NB, CH,
                                           W0, W1, W2, scale, Wh);
  // K4: layer-0 GEMM || bucket sort || bias0 prep
  k_sort_gemm0<<<nb64 + NB + 1, 512, 0, stream>>>(ebuf, bbase, csrs, rowst, dinv,
                                                  N, E, NB, nb64, b0, shift, W0, bias0p,
                                                  x, Wh, m);
  // layer 0 gather
  gather_squash<<<(N+7)/8, 256, 0, stream>>>(m, rowst, csrs, dinv, bias0p, tar, h, attn, N);
  // readout(0) || gemm(1)
  k_ro_gemm<<<nb64 + G, 512, 0, stream>>>(h, attn, gstart, grep, Wh + 16384, m, N, nb64);
  gather_squash<<<(N+7)/8, 256, 0, stream>>>(m, rowst, csrs, dinv, b1, tar + 128, h, attn, N);
  // readout(1) || gemm(2)
  k_ro_gemm<<<nb64 + G, 512, 0, stream>>>(h, attn, gstart, grep, Wh + 2*16384, m, N, nb64);
  gather_squash<<<(N+7)/8, 256, 0, stream>>>(m, rowst, csrs, dinv, b2, tar + 256, h, attn, N);
  // readout(2) only
  k_ro_gemm<<<G, 512, 0, stream>>>(h, attn, gstart, grep, Wh, m, N, 0);
  classify<<<G, 128, 0, stream>>>(grep, l1w, l1b, l2w, l2b, out);
}

// Round 17
// 240.738 us; speedup vs baseline: 2.4528x; 1.0070x over previous
//
#include <hip/hip_runtime.h>
#include <hip/hip_bf16.h>
#include <math.h>

#define BN_EPS 1e-5f
#define NCHUNK 256

typedef __attribute__((ext_vector_type(8)))  short short8v;
typedef __attribute__((ext_vector_type(16))) float f32x16;

__device__ __forceinline__ unsigned short f2bf(float f){
  union { float f; unsigned u; } v; v.f = f;
  unsigned r = v.u + 0x7FFFu + ((v.u >> 16) & 1u);
  return (unsigned short)(r >> 16);
}
__device__ __forceinline__ float2 bfpair(unsigned u){
  union { unsigned u; float f; } lo, hi;
  lo.u = u << 16;
  hi.u = u & 0xFFFF0000u;
  return make_float2(lo.f, hi.f);
}
__device__ __forceinline__ unsigned packbf(float a, float b){
  return (unsigned)f2bf(a) | ((unsigned)f2bf(b) << 16);
}

// ================= device bodies (shared across packed kernels) =================

template<int CVT>
__device__ __forceinline__ void gemm_body(int bid, int tid,
    const float* __restrict__ A32, const unsigned short* __restrict__ A16,
    const unsigned short* __restrict__ Bh, unsigned short* __restrict__ C, int N,
    unsigned short* Ah){
  int r0 = bid * 64;
  int w = tid >> 6, lane = tid & 63;
  int rt = w & 1;
  int ct = (w >> 1) * 32;
  int lrow = 32*rt + (lane & 31);
  int khalf = lane >> 5;
  int c0 = ct + (lane & 31);
  const unsigned short* bh0 = Bh + (size_t)c0*128 + khalf*8;

  short8v bhf[8];
  #pragma unroll
  for (int s = 0; s < 8; ++s) bhf[s] = *(const short8v*)(bh0 + s*16);

  if (CVT){
    #pragma unroll
    for (int it = 0; it < 4; ++it){
      int idx = tid + it*512;
      int row = idx >> 5;
      int c4  = idx & 31;
      int r = r0 + row;
      float4 av = (r < N) ? *(const float4*)(A32 + (size_t)r*128 + c4*4)
                          : make_float4(0.f,0.f,0.f,0.f);
      int byte0 = (c4*8) ^ ((row & 15) << 4);
      uint2 p = make_uint2(packbf(av.x, av.y), packbf(av.z, av.w));
      *(uint2*)((char*)Ah + row*256 + byte0) = p;
    }
  } else {
    #pragma unroll
    for (int it = 0; it < 2; ++it){
      int idx = tid + it*512;
      int row = idx >> 4;
      int c8  = idx & 15;
      int r = r0 + row;
      uint4 v = (r < N) ? *(const uint4*)(A16 + (size_t)r*128 + c8*8)
                        : make_uint4(0,0,0,0);
      int byte0 = (c8*16) ^ ((row & 15) << 4);
      *(uint4*)((char*)Ah + row*256 + byte0) = v;
    }
  }
  __syncthreads();

  f32x16 acc = {};
  const char* AhB = (const char*)Ah + lrow*256;
  int sw = (lrow & 15) << 4;
  #pragma unroll
  for (int s = 0; s < 8; ++s){
    int abyte = (s*32 + khalf*16) ^ sw;
    short8v a = *(const short8v*)(AhB + abyte);
    acc = __builtin_amdgcn_mfma_f32_32x32x16_bf16(a, bhf[s], acc, 0, 0, 0);
  }

  #pragma unroll
  for (int r = 0; r < 16; ++r){
    int row = r0 + 32*rt + (r & 3) + 8*(r >> 2) + 4*khalf;
    if (row < N) C[(size_t)row*128 + c0] = f2bf(acc[r]);
  }
}

__device__ __forceinline__ void readout_body(int g, int tid,
    const unsigned short* __restrict__ h, const float* __restrict__ attn,
    const int* __restrict__ gstart, float* __restrict__ grep, char* smem){
  float2* sws = (float2*)smem;
  float2* ssm = sws + 8*64;
  float2* smx = ssm + 8*64;
  int t = tid & 63, grp = tid >> 6;
  int a = gstart[g], b = gstart[g+1];
  float wsx = 0.f, wsy = 0.f, smx_ = 0.f, smy_ = 0.f;
  float mxx = -INFINITY, mxy = -INFINITY;
  for (int n = a + grp; n < b; n += 8){
    unsigned u = ((const unsigned*)(h + (size_t)n*128))[t];
    float2 v = bfpair(u);
    float at = attn[n];
    wsx += at*v.x; wsy += at*v.y;
    smx_ += v.x;  smy_ += v.y;
    mxx = fmaxf(mxx, v.x); mxy = fmaxf(mxy, v.y);
  }
  sws[grp*64 + t] = make_float2(wsx, wsy);
  ssm[grp*64 + t] = make_float2(smx_, smy_);
  smx[grp*64 + t] = make_float2(mxx, mxy);
  __syncthreads();
  if (grp == 0){
    #pragma unroll
    for (int j = 1; j < 8; ++j){
      float2 ow = sws[j*64 + t], os = ssm[j*64 + t], om = smx[j*64 + t];
      wsx += ow.x; wsy += ow.y;
      smx_ += os.x; smy_ += os.y;
      mxx = fmaxf(mxx, om.x); mxy = fmaxf(mxy, om.y);
    }
    int cnt = b - a;
    float inv = 1.f / fmaxf((float)cnt, 1.f);
    if (cnt == 0){ mxx = 0.f; mxy = 0.f; }
    grep[(size_t)g*384 + t*2]           += wsx;
    grep[(size_t)g*384 + t*2 + 1]       += wsy;
    grep[(size_t)g*384 + 128 + t*2]     += smx_*inv;
    grep[(size_t)g*384 + 128 + t*2 + 1] += smy_*inv;
    grep[(size_t)g*384 + 256 + t*2]     += mxx;
    grep[(size_t)g*384 + 256 + t*2 + 1] += mxy;
  }
}

__device__ __forceinline__ void sort_body(int b, int tid,
    const unsigned* __restrict__ ebuf, const int* __restrict__ bbase,
    int* __restrict__ csrs, int* __restrict__ rowstart, float* __restrict__ dinv,
    int N, int E, int NB, int* cnt, int* pref){
  bool act = tid < 256;
  int base = bbase[b], end = bbase[b+1], len = end - base;
  if (act) cnt[tid] = 0;
  __syncthreads();
  if (act) for (int i = tid; i < len; i += 256)
    atomicAdd(&cnt[ebuf[base + i] >> 24], 1);
  __syncthreads();
  int v = 0;
  if (act){ v = cnt[tid]; pref[tid] = v; }
  __syncthreads();
  for (int d = 1; d < 256; d <<= 1){
    int u = 0;
    if (act && tid >= d) u = pref[tid-d];
    __syncthreads();
    if (act) pref[tid] += u;
    __syncthreads();
  }
  if (act){
    int excl = pref[tid] - v;
    int node = b*256 + tid;
    if (node < N){
      rowstart[node] = base + excl;
      dinv[node] = rsqrtf((float)v + 1.0f);
    }
    cnt[tid] = excl;
  }
  __syncthreads();
  if (act) for (int i = tid; i < len; i += 256){
    unsigned r = ebuf[base + i];
    int pos = atomicAdd(&cnt[r >> 24], 1);
    csrs[base + pos] = (int)(r & 0xFFFFFFu);
  }
  if (b == NB-1 && tid == 0) rowstart[N] = E;
}

// ================= packed kernels =================

__global__ __launch_bounds__(256) void k_pre1(const int* __restrict__ dst,
                                              int* __restrict__ hist2, int E, int NB, int CH,
                                              const float* __restrict__ x,
                                              float* __restrict__ part, int total4,
                                              float* __restrict__ grep, int zt4){
  int tid = threadIdx.x;
  if (blockIdx.x < NCHUNK){
    __shared__ int lh[512];
    for (int i = tid; i < NB; i += 256) lh[i] = 0;
    __syncthreads();
    int c = blockIdx.x;
    int e0 = c*CH, e1 = min(e0 + CH, E);
    for (int e = e0 + tid; e < e1; e += 256)
      atomicAdd(&lh[dst[e] >> 8], 1);
    __syncthreads();
    for (int i = tid; i < NB; i += 256)
      hist2[c*NB + i] = lh[i];
  } else if (blockIdx.x < NCHUNK + 512){
    const float4* x4 = (const float4*)x;
    int bb = blockIdx.x - NCHUNK;
    int stride = 512 * 256;
    float4 s = make_float4(0.f,0.f,0.f,0.f);
    float4 q = make_float4(0.f,0.f,0.f,0.f);
    for (int idx = bb*256 + tid; idx < total4; idx += stride){
      float4 v = x4[idx];
      s.x += v.x; s.y += v.y; s.z += v.z; s.w += v.w;
      q.x += v.x*v.x; q.y += v.y*v.y; q.z += v.z*v.z; q.w += v.w*v.w;
    }
    __shared__ float4 shs[256], shq[256];
    shs[tid] = s; shq[tid] = q;
    __syncthreads();
    if (tid < 32){
      int c4 = tid;
      float4 ts = shs[c4], tq = shq[c4];
      #pragma unroll
      for (int j = 1; j < 8; ++j){
        float4 os = shs[c4 + j*32], oq = shq[c4 + j*32];
        ts.x += os.x; ts.y += os.y; ts.z += os.z; ts.w += os.w;
        tq.x += oq.x; tq.y += oq.y; tq.z += oq.z; tq.w += oq.w;
      }
      float* pb = part + (size_t)bb * 256;
      *(float4*)(pb + c4*4)       = ts;
      *(float4*)(pb + 128 + c4*4) = tq;
    }
  } else {
    float4* g4 = (float4*)grep;
    int bb = blockIdx.x - NCHUNK - 512;
    int stride = 24 * 256;
    float4 z = make_float4(0.f,0.f,0.f,0.f);
    for (int idx = bb*256 + tid; idx < zt4; idx += stride) g4[idx] = z;
  }
}

__global__ __launch_bounds__(512) void k_pre2(const int* __restrict__ hist2,
                                              int* __restrict__ offs2,
                                              int* __restrict__ bbase, int NB, int E,
                                              const float* __restrict__ part,
                                              const float* __restrict__ gamma,
                                              const float* __restrict__ beta,
                                              float* __restrict__ scale,
                                              float* __restrict__ shift, int N,
                                              const int* __restrict__ batch,
                                              int* __restrict__ gstart, int G){
  int t = threadIdx.x;
  if (blockIdx.x == 0){
    __shared__ int tot[512];
    int b = t;
    int total = 0;
    if (b < NB){
      for (int c = 0; c < NCHUNK; c += 8){
        int h0 = hist2[(c+0)*NB + b], h1 = hist2[(c+1)*NB + b];
        int h2 = hist2[(c+2)*NB + b], h3 = hist2[(c+3)*NB + b];
        int h4 = hist2[(c+4)*NB + b], h5 = hist2[(c+5)*NB + b];
        int h6 = hist2[(c+6)*NB + b], h7 = hist2[(c+7)*NB + b];
        total += ((h0+h1)+(h2+h3)) + ((h4+h5)+(h6+h7));
      }
    }
    tot[b] = (b < NB) ? total : 0;
    __syncthreads();
    int v = tot[b];
    for (int d = 1; d < 512; d <<= 1){
      int u = (b >= d) ? tot[b-d] : 0;
      __syncthreads();
      tot[b] += u;
      __syncthreads();
    }
    if (b < NB){
      int base = tot[b] - v;
      bbase[b] = base;
      int run = base;
      for (int c = 0; c < NCHUNK; ++c){
        offs2[c*NB + b] = run;
        run += hist2[c*NB + b];
      }
    }
    if (b == 0) bbase[NB] = E;
  } else if (blockIdx.x == 1){
    if (t < 256){
      float a0=0.f,a1=0.f,a2=0.f,a3=0.f,a4=0.f,a5=0.f,a6=0.f,a7=0.f;
      for (int b = 0; b < 512; b += 8){
        a0 += part[(size_t)(b+0)*256 + t];
        a1 += part[(size_t)(b+1)*256 + t];
        a2 += part[(size_t)(b+2)*256 + t];
        a3 += part[(size_t)(b+3)*256 + t];
        a4 += part[(size_t)(b+4)*256 + t];
        a5 += part[(size_t)(b+5)*256 + t];
        a6 += part[(size_t)(b+6)*256 + t];
        a7 += part[(size_t)(b+7)*256 + t];
      }
      float acc = ((a0+a1)+(a2+a3)) + ((a4+a5)+(a6+a7));
      __shared__ float sh[256];
      sh[t] = acc;
      __syncthreads();
      if (t < 128){
        float mu  = sh[t] / (float)N;
        float var = sh[t+128] / (float)N - mu*mu;
        float sc  = gamma[t] * rsqrtf(var + BN_EPS);
        scale[t] = sc;
        shift[t] = beta[t] - mu*sc;
      }
    }
  } else {
    int g = (blockIdx.x - 2)*512 + t;
    if (g <= G){
      int lo = 0, hi = N;
      while (lo < hi){ int mid = (lo+hi)>>1; if (batch[mid] < g) lo = mid+1; else hi = mid; }
      gstart[g] = lo;
    }
  }
}

__global__ __launch_bounds__(256) void k_pre3(const int* __restrict__ src,
                                              const int* __restrict__ dst,
                                              const int* __restrict__ offs2,
                                              unsigned* __restrict__ ebuf,
                                              int E, int NB, int CH,
                                              const float* __restrict__ W0,
                                              const float* __restrict__ W1,
                                              const float* __restrict__ W2,
                                              const float* __restrict__ scale,
                                              unsigned short* __restrict__ Wh){
  int tid = threadIdx.x;
  if (blockIdx.x < NCHUNK){
    __shared__ int lcur[512];
    int c = blockIdx.x;
    for (int i = tid; i < NB; i += 256) lcur[i] = offs2[c*NB + i];
    __syncthreads();
    int e0 = c*CH, e1 = min(e0 + CH, E);
    for (int e = e0 + tid; e < e1; e += 256){
      int d = dst[e];
      int b = d >> 8;
      int pos = atomicAdd(&lcur[b], 1);
      ebuf[pos] = ((unsigned)(d & 255) << 24) | (unsigned)src[e];
    }
  } else {
    int idx = (blockIdx.x - NCHUNK)*256 + tid;
    int l = idx >> 14, r = idx & 16383, c = r >> 7, k = r & 127;
    const float* W = (l==0) ? W0 : (l==1) ? W1 : W2;
    float v = W[k*128 + c];
    if (l == 0) v *= scale[k];
    Wh[idx] = f2bf(v);
  }
}

__global__ __launch_bounds__(512) void k_sort_gemm0(const unsigned* __restrict__ ebuf,
                                                    const int* __restrict__ bbase,
                                                    int* __restrict__ csrs,
                                                    int* __restrict__ rowstart,
                                                    float* __restrict__ dinv,
                                                    int N, int E, int NB, int nb64,
                                                    const float* __restrict__ b0,
                                                    const float* __restrict__ shift,
                                                    const float* __restrict__ W0,
                                                    float* __restrict__ bias0p,
                                                    const float* __restrict__ x,
                                                    const unsigned short* __restrict__ Wh,
                                                    unsigned short* __restrict__ m){
  __shared__ float4 smem4[1024];
  int tid = threadIdx.x;
  if ((int)blockIdx.x < nb64){
    gemm_body<1>(blockIdx.x, tid, x, nullptr, Wh, m, N, (unsigned short*)smem4);
  } else if ((int)blockIdx.x < nb64 + NB){
    int* cnt = (int*)smem4;
    int* pref = cnt + 256;
    sort_body(blockIdx.x - nb64, tid, ebuf, bbase, csrs, rowstart, dinv, N, E, NB, cnt, pref);
  } else {
    float* sh = (float*)smem4;
    if (tid < 128) sh[tid] = shift[tid];
    __syncthreads();
    if (tid < 128){
      float s = b0[tid];
      for (int c = 0; c < 128; ++c) s += sh[c] * W0[c*128 + tid];
      bias0p[tid] = s;
    }
  }
}

__global__ __launch_bounds__(512) void k_ro_gemm(const unsigned short* __restrict__ h,
                                                 const float* __restrict__ attn,
                                                 const int* __restrict__ gstart,
                                                 float* __restrict__ grep,
                                                 const unsigned short* __restrict__ Bh,
                                                 unsigned short* __restrict__ m,
                                                 int N, int nb64){
  __shared__ float4 smem4[1024];
  if ((int)blockIdx.x < nb64){
    gemm_body<0>(blockIdx.x, threadIdx.x, nullptr, h, Bh, m, N, (unsigned short*)smem4);
  } else {
    readout_body(blockIdx.x - nb64, threadIdx.x, h, attn, gstart, grep, (char*)smem4);
  }
}

// ---------------- fused aggregation + bias + squash + attention ----------------
// Branch-free 8-deep gather batches: padded lanes re-load an in-flight row
// (cache hit, weight 0) so a typical deg<=8 node is ONE issue round.
__global__ __launch_bounds__(256) void gather_squash(
    const unsigned short* __restrict__ m, const int* __restrict__ rowstart,
    const int* __restrict__ csrs, const float* __restrict__ dinv,
    const float* __restrict__ bias, const float* __restrict__ tar,
    unsigned short* __restrict__ h, float* __restrict__ attn, int N){
  int node = blockIdx.x*8 + (threadIdx.x >> 5);
  if (node >= N) return;
  int lane = threadIdx.x & 31;
  const uint2* m2 = (const uint2*)m;
  float dv = dinv[node];
  float sn = dv*dv;
  uint2 sv = m2[(size_t)node*32 + lane];
  float2 p0 = bfpair(sv.x), p1 = bfpair(sv.y);
  float a0 = p0.x*sn, a1 = p0.y*sn, a2 = p1.x*sn, a3 = p1.y*sn;
  int j0 = rowstart[node], j1 = rowstart[node+1];

  for (int base = j0; base < j1; base += 32){
    int cnt = j1 - base; if (cnt > 32) cnt = 32;
    int li = base + min(lane, cnt-1);
    int sidx = csrs[li];
    float swt = (lane < cnt) ? dinv[sidx] * dv : 0.f;

    for (int t = 0; t < cnt; t += 8){
      int s_[8]; float w_[8];
      #pragma unroll
      for (int i = 0; i < 8; ++i){
        int idx = min(t + i, cnt - 1);
        s_[i] = __shfl(sidx, idx, 32);
        w_[i] = (t + i < cnt) ? __shfl(swt, idx, 32) : 0.f;
      }
      uint2 u_[8];
      #pragma unroll
      for (int i = 0; i < 8; ++i) u_[i] = m2[(size_t)s_[i]*32 + lane];
      #pragma unroll
      for (int i = 0; i < 8; ++i){
        float2 q0 = bfpair(u_[i].x), q1 = bfpair(u_[i].y);
        a0 += w_[i]*q0.x; a1 += w_[i]*q0.y;
        a2 += w_[i]*q1.x; a3 += w_[i]*q1.y;
      }
    }
  }

  float4 bv = ((const float4*)bias)[lane];
  a0 += bv.x; a1 += bv.y; a2 += bv.z; a3 += bv.w;
  float n2 = a0*a0 + a1*a1 + a2*a2 + a3*a3;
  #pragma unroll
  for (int o = 16; o > 0; o >>= 1) n2 += __shfl_xor(n2, o);
  float sc = (n2/(1.f+n2)) * rsqrtf(n2 + 1e-12f);
  float h0 = a0*sc, h1 = a1*sc, h2 = a2*sc, h3 = a3*sc;
  ((uint2*)(h + (size_t)node*128))[lane] = make_uint2(packbf(h0,h1), packbf(h2,h3));
  float4 tv = ((const float4*)tar)[lane];
  float at = h0*tv.x + h1*tv.y + h2*tv.z + h3*tv.w;
  #pragma unroll
  for (int o = 16; o > 0; o >>= 1) at += __shfl_xor(at, o);
  if (lane == 0) attn[node] = at;
}

// ---------------- classifier head + log_softmax ----------------
__global__ __launch_bounds__(128) void classify(const float* __restrict__ grep,
                                                const float* __restrict__ w1, const float* __restrict__ b1,
                                                const float* __restrict__ w2, const float* __restrict__ b2,
                                                float* __restrict__ out){
  int g = blockIdx.x, t = threadIdx.x;
  __shared__ float gr[384];
  for (int i = t; i < 384; i += 128) gr[i] = grep[(size_t)g*384 + i];
  __syncthreads();
  float z = b1[t];
  for (int k = 0; k < 384; ++k) z += gr[k]*w1[k*128 + t];
  z = fmaxf(z, 0.f);
  float c0 = z*w2[t*2 + 0], c1 = z*w2[t*2 + 1];
  #pragma unroll
  for (int o = 32; o > 0; o >>= 1){ c0 += __shfl_xor(c0, o); c1 += __shfl_xor(c1, o); }
  __shared__ float r0s[2], r1s[2];
  if ((t & 63) == 0){ r0s[t>>6] = c0; r1s[t>>6] = c1; }
  __syncthreads();
  if (t == 0){
    float z0 = r0s[0] + r0s[1] + b2[0];
    float z1 = r1s[0] + r1s[1] + b2[1];
    float mm = fmaxf(z0, z1);
    float lse = mm + logf(expf(z0-mm) + expf(z1-mm));
    out[g*2 + 0] = z0 - lse;
    out[g*2 + 1] = z1 - lse;
  }
}

extern "C" void kernel_launch(void* const* d_in, const int* in_sizes, int n_in,
                              void* d_out, int out_size, void* d_ws, size_t ws_size,
                              hipStream_t stream) {
  const float* x     = (const float*)d_in[0];
  const int*   ei    = (const int*)d_in[1];
  const int*   batch = (const int*)d_in[2];
  const float* gamma = (const float*)d_in[3];
  const float* beta  = (const float*)d_in[4];
  const float* W0    = (const float*)d_in[5];
  const float* b0    = (const float*)d_in[6];
  const float* W1    = (const float*)d_in[7];
  const float* b1    = (const float*)d_in[8];
  const float* W2    = (const float*)d_in[9];
  const float* b2    = (const float*)d_in[10];
  const float* tar   = (const float*)d_in[11];
  const float* l1w   = (const float*)d_in[12];
  const float* l1b   = (const float*)d_in[13];
  const float* l2w   = (const float*)d_in[14];
  const float* l2b   = (const float*)d_in[15];
  float* out = (float*)d_out;

  int N = in_sizes[0] / 128;
  int E = in_sizes[1] / 2;
  int G = out_size / 2;
  const int* srcp = ei;
  const int* dstp = ei + E;

  char* wsb = (char*)d_ws;
  size_t off = 0;
  auto alloc = [&](size_t bytes)->char*{
    char* p = wsb + off; off += (bytes + 255) & ~(size_t)255; return p;
  };
  unsigned short* h = (unsigned short*)alloc((size_t)N*128*2);
  unsigned short* m = (unsigned short*)alloc((size_t)N*128*2);
  float* attn    = (float*)alloc((size_t)N*4);
  float* dinv    = (float*)alloc((size_t)N*4);
  int*   rowst   = (int*)  alloc((size_t)(N+1)*4);
  int*   csrs    = (int*)  alloc((size_t)E*4);
  unsigned* ebuf = (unsigned*)alloc((size_t)E*4);
  int*   hist2   = (int*)  alloc((size_t)NCHUNK*512*4);
  int*   offs2   = (int*)  alloc((size_t)NCHUNK*512*4);
  int*   bbase   = (int*)  alloc(513*4);
  int*   gstart  = (int*)  alloc((size_t)(G+1)*4);
  float* grep    = (float*)alloc((size_t)G*384*4);
  float* stats   = (float*)alloc(2*128*4);
  float* bias0p  = (float*)alloc(128*4);
  float* part    = (float*)alloc((size_t)512*256*4);
  unsigned short* Wh = (unsigned short*)alloc(3*16384*2);
  (void)ws_size;

  float* scale  = stats;
  float* shift  = stats + 128;

  int NB = (N + 255) >> 8;
  int CH = (E + NCHUNK - 1) / NCHUNK;
  int nb64 = (N + 63) / 64;
  int zt4 = (G*384) / 4;

  k_pre1<<<NCHUNK + 512 + 24, 256, 0, stream>>>(dstp, hist2, E, NB, CH, x, part, N*32, grep, zt4);
  k_pre2<<<4, 512, 0, stream>>>(hist2, offs2, bbase, NB, E,
                                part, gamma, beta, scale, shift, N, batch, gstart, G);
  k_pre3<<<NCHUNK + 192, 256, 0, stream>>>(srcp, dstp, offs2, ebuf, E, NB, CH,
                                           W0, W1, W2, scale, Wh);
  k_sort_gemm0<<<nb64 + NB + 1, 512, 0, stream>>>(ebuf, bbase, csrs, rowst, dinv,
                                                  N, E, NB, nb64, b0, shift, W0, bias0p,
                                                  x, Wh, m);
  gather_squash<<<(N+7)/8, 256, 0, stream>>>(m, rowst, csrs, dinv, bias0p, tar, h, attn, N);
  k_ro_gemm<<<nb64 + G, 512, 0, stream>>>(h, attn, gstart, grep, Wh + 16384, m, N, nb64);
  gather_squash<<<(N+7)/8, 256, 0, stream>>>(m, rowst, csrs, dinv, b1, tar + 128, h, attn, N);
  k_ro_gemm<<<nb64 + G, 512, 0, stream>>>(h, attn, gstart, grep, Wh + 2*16384, m, N, nb64);
  gather_squash<<<(N+7)/8, 256, 0, stream>>>(m, rowst, csrs, dinv, b2, tar + 256, h, attn, N);
  k_ro_gemm<<<G, 512, 0, stream>>>(h, attn, gstart, grep, Wh, m, N, 0);
  classify<<<G, 128, 0, stream>>>(grep, l1w, l1b, l2w, l2b, out);
}